// Round 1
// baseline (2125.480 us; speedup 1.0000x reference)
//
#include <hip/hip_runtime.h>
#include <math.h>

#define DIM_ 1024
#define HEADS_ 16
#define HD_ 64
#define B_ 8
#define N_ 1024
#define M_TOT 8192
#define QKV_SZ (B_*HEADS_*N_*HD_)   // 8388608 floats per array

// ---------------- QKV GEMM: qkv[m,f] = sum_c x[m,c]*Wqkv[f,c] ----------------
// Scatter epilogue into q/k/v arrays laid out (B, H, N, HD) row-major.
__global__ __launch_bounds__(256) void qkv_gemm_k(const float* __restrict__ A,
                                                  const float* __restrict__ W,
                                                  float* __restrict__ q,
                                                  float* __restrict__ k,
                                                  float* __restrict__ v) {
  __shared__ float As[16][68];
  __shared__ float Bs[16][68];
  const int tid = threadIdx.x;
  const int m0 = blockIdx.y * 64;
  const int f0 = blockIdx.x * 64;
  const int tx = tid & 15, ty = tid >> 4;
  const int lr = tid >> 2, lc = (tid & 3) * 4;
  float acc[4][4] = {};
  const float* Aptr = A + (long)(m0 + lr) * DIM_ + lc;
  const float* Wptr = W + (long)(f0 + lr) * DIM_ + lc;
  for (int k0 = 0; k0 < DIM_; k0 += 16) {
    float4 av = *(const float4*)(Aptr + k0);
    float4 bv = *(const float4*)(Wptr + k0);
    As[lc+0][lr]=av.x; As[lc+1][lr]=av.y; As[lc+2][lr]=av.z; As[lc+3][lr]=av.w;
    Bs[lc+0][lr]=bv.x; Bs[lc+1][lr]=bv.y; Bs[lc+2][lr]=bv.z; Bs[lc+3][lr]=bv.w;
    __syncthreads();
#pragma unroll
    for (int kk = 0; kk < 16; ++kk) {
      float4 a4 = *(const float4*)&As[kk][ty*4];
      float4 b4 = *(const float4*)&Bs[kk][tx*4];
      float a[4] = {a4.x, a4.y, a4.z, a4.w};
      float b[4] = {b4.x, b4.y, b4.z, b4.w};
#pragma unroll
      for (int i = 0; i < 4; ++i)
#pragma unroll
        for (int j = 0; j < 4; ++j) acc[i][j] = fmaf(a[i], b[j], acc[i][j]);
    }
    __syncthreads();
  }
  // f-tile is 64-aligned -> whole block maps to one of q/k/v and one head
  const int qsel = f0 >> 10;
  const int h = (f0 & 1023) >> 6;
  float* outp = (qsel == 0) ? q : ((qsel == 1) ? k : v);
#pragma unroll
  for (int i = 0; i < 4; ++i) {
    int m = m0 + ty*4 + i;
    int bb = m >> 10, n = m & 1023;
    float4 val = make_float4(acc[i][0], acc[i][1], acc[i][2], acc[i][3]);
    *(float4*)(outp + ((long)(bb*HEADS_ + h)*N_ + n)*HD_ + tx*4) = val;
  }
}

// ---------------- Proj GEMM: out[m,o] = sum_c att[m,c]*Wproj[o,c] + bias[o] --
__global__ __launch_bounds__(256) void proj_gemm_k(const float* __restrict__ A,
                                                   const float* __restrict__ W,
                                                   const float* __restrict__ bias,
                                                   float* __restrict__ out) {
  __shared__ float As[16][68];
  __shared__ float Bs[16][68];
  const int tid = threadIdx.x;
  const int m0 = blockIdx.y * 64;
  const int o0 = blockIdx.x * 64;
  const int tx = tid & 15, ty = tid >> 4;
  const int lr = tid >> 2, lc = (tid & 3) * 4;
  float acc[4][4] = {};
  const float* Aptr = A + (long)(m0 + lr) * DIM_ + lc;
  const float* Wptr = W + (long)(o0 + lr) * DIM_ + lc;
  for (int k0 = 0; k0 < DIM_; k0 += 16) {
    float4 av = *(const float4*)(Aptr + k0);
    float4 bv = *(const float4*)(Wptr + k0);
    As[lc+0][lr]=av.x; As[lc+1][lr]=av.y; As[lc+2][lr]=av.z; As[lc+3][lr]=av.w;
    Bs[lc+0][lr]=bv.x; Bs[lc+1][lr]=bv.y; Bs[lc+2][lr]=bv.z; Bs[lc+3][lr]=bv.w;
    __syncthreads();
#pragma unroll
    for (int kk = 0; kk < 16; ++kk) {
      float4 a4 = *(const float4*)&As[kk][ty*4];
      float4 b4 = *(const float4*)&Bs[kk][tx*4];
      float a[4] = {a4.x, a4.y, a4.z, a4.w};
      float b[4] = {b4.x, b4.y, b4.z, b4.w};
#pragma unroll
      for (int i = 0; i < 4; ++i)
#pragma unroll
        for (int j = 0; j < 4; ++j) acc[i][j] = fmaf(a[i], b[j], acc[i][j]);
    }
    __syncthreads();
  }
  float4 bv = *(const float4*)(bias + o0 + tx*4);
#pragma unroll
  for (int i = 0; i < 4; ++i) {
    int m = m0 + ty*4 + i;
    float4 val = make_float4(acc[i][0]+bv.x, acc[i][1]+bv.y, acc[i][2]+bv.z, acc[i][3]+bv.w);
    *(float4*)(out + (long)m*DIM_ + o0 + tx*4) = val;
  }
}

// ---------------- RoPE table (fp64 for fidelity; angles reach ~1608 rad) -----
__global__ void rope_table_k(float* cs, float* sn) {
  int i = threadIdx.x;
  if (i < 256) {
    int pos = i >> 3, j = i & 7;
    double u = -1.0 + (double)pos * (2.0/31.0);
    double ang = u * ((1.0 + 73.0*(double)j) * 3.14159265358979323846);
    cs[i] = (float)cos(ang);
    sn[i] = (float)sin(ang);
  }
}

// ---------------- RoPE apply (in-place on q and k) ---------------------------
// pair p in [0,16): p<8 -> freq from grid-h (th[gh,p]); p>=8 -> grid-w (th[gw,p-8])
__global__ __launch_bounds__(256) void rope_apply_k(float* __restrict__ q,
                                                    float* __restrict__ kk,
                                                    const float* __restrict__ cs,
                                                    const float* __restrict__ sn) {
  int idx = blockIdx.x * 256 + threadIdx.x;   // 2 arrays * 131072 rows * 16 pairs
  int p = idx & 15;
  int rowg = idx >> 4;
  int arr = rowg >> 17;
  int row = rowg & ((1 << 17) - 1);
  int n = row & 1023;
  int pos = (p < 8) ? (n >> 5) : (n & 31);
  int j = p & 7;
  float c = cs[pos*8 + j], s = sn[pos*8 + j];
  float* base = (arr ? kk : q) + (long)row * HD_ + 2*p;
  float2 t = *(float2*)base;
  float2 o;
  o.x = t.x * c - t.y * s;
  o.y = t.y * c + t.x * s;
  *(float2*)base = o;
}

// ---------------- Flash attention: one block per (b,h, 64-row q-tile) --------
__global__ __launch_bounds__(256) void attn_k(const float* __restrict__ q,
                                              const float* __restrict__ k,
                                              const float* __restrict__ v,
                                              float* __restrict__ attout) {
  __shared__ float Ks[64][68];   // K tile, later reused for V tile
  __shared__ float Ps[64][67];   // probabilities (stride 67 to kill bank conflicts)
  const int tid = threadIdx.x;
  const int qt = blockIdx.x;     // 0..15
  const int bh = blockIdx.y;     // 0..127
  const long hoff = (long)bh * N_ * HD_;
  const float* qb = q + hoff;
  const float* kb = k + hoff;
  const float* vb = v + hoff;
  const int r = tid >> 2, q4 = tid & 3;   // 4 threads per query row
  float qreg[64];
  {
    const float* qrow = qb + (long)(qt*64 + r) * HD_;
#pragma unroll
    for (int i = 0; i < 16; ++i) {
      float4 t = *(const float4*)(qrow + i*4);
      qreg[i*4+0] = t.x * 0.125f;
      qreg[i*4+1] = t.y * 0.125f;
      qreg[i*4+2] = t.z * 0.125f;
      qreg[i*4+3] = t.w * 0.125f;
    }
  }
  float o[16];
#pragma unroll
  for (int i = 0; i < 16; ++i) o[i] = 0.f;
  float mrow = -INFINITY, lrow = 0.f;
  const int llr = tid >> 2, llc = (tid & 3) * 16;  // tile loads: 16 floats/thread
  for (int t = 0; t < 16; ++t) {
    {  // load K tile
      const float* src = kb + (long)(t*64 + llr) * HD_ + llc;
#pragma unroll
      for (int i = 0; i < 4; ++i)
        *(float4*)&Ks[llr][llc + i*4] = *(const float4*)(src + i*4);
    }
    __syncthreads();
    float s[16];
#pragma unroll
    for (int c = 0; c < 16; ++c) {
      int col = q4*16 + c;
      const float4* kr = (const float4*)&Ks[col][0];
      float accv = 0.f;
#pragma unroll
      for (int d4 = 0; d4 < 16; ++d4) {
        float4 kv = kr[d4];
        accv = fmaf(qreg[d4*4+0], kv.x, accv);
        accv = fmaf(qreg[d4*4+1], kv.y, accv);
        accv = fmaf(qreg[d4*4+2], kv.z, accv);
        accv = fmaf(qreg[d4*4+3], kv.w, accv);
      }
      s[c] = accv;
    }
    float ms = s[0];
#pragma unroll
    for (int c = 1; c < 16; ++c) ms = fmaxf(ms, s[c]);
    ms = fmaxf(ms, __shfl_xor(ms, 1));
    ms = fmaxf(ms, __shfl_xor(ms, 2));
    float mnew = fmaxf(mrow, ms);
    float corr = expf(mrow - mnew);     // exp(-inf)=0 on first tile
    float psum = 0.f;
#pragma unroll
    for (int c = 0; c < 16; ++c) {
      float pv = expf(s[c] - mnew);
      s[c] = pv;
      psum += pv;
    }
    psum += __shfl_xor(psum, 1);
    psum += __shfl_xor(psum, 2);
    lrow = lrow * corr + psum;
    mrow = mnew;
#pragma unroll
    for (int i = 0; i < 16; ++i) o[i] *= corr;
#pragma unroll
    for (int c = 0; c < 16; ++c) Ps[r][q4*16 + c] = s[c];
    __syncthreads();                    // everyone done reading Ks, Ps written
    {  // load V tile over Ks
      const float* src = vb + (long)(t*64 + llr) * HD_ + llc;
#pragma unroll
      for (int i = 0; i < 4; ++i)
        *(float4*)&Ks[llr][llc + i*4] = *(const float4*)(src + i*4);
    }
    __syncthreads();                    // V ready
#pragma unroll
    for (int kk2 = 0; kk2 < 64; ++kk2) {
      float pv = Ps[r][kk2];
      const float4* vr = (const float4*)&Ks[kk2][q4*16];
      float4 v0 = vr[0], v1 = vr[1], v2 = vr[2], v3 = vr[3];
      o[0]  = fmaf(pv, v0.x, o[0]);  o[1]  = fmaf(pv, v0.y, o[1]);
      o[2]  = fmaf(pv, v0.z, o[2]);  o[3]  = fmaf(pv, v0.w, o[3]);
      o[4]  = fmaf(pv, v1.x, o[4]);  o[5]  = fmaf(pv, v1.y, o[5]);
      o[6]  = fmaf(pv, v1.z, o[6]);  o[7]  = fmaf(pv, v1.w, o[7]);
      o[8]  = fmaf(pv, v2.x, o[8]);  o[9]  = fmaf(pv, v2.y, o[9]);
      o[10] = fmaf(pv, v2.z, o[10]); o[11] = fmaf(pv, v2.w, o[11]);
      o[12] = fmaf(pv, v3.x, o[12]); o[13] = fmaf(pv, v3.y, o[13]);
      o[14] = fmaf(pv, v3.z, o[14]); o[15] = fmaf(pv, v3.w, o[15]);
    }
    __syncthreads();                    // PV reads done -> next iter may reuse Ks/Ps
  }
  float inv = 1.0f / lrow;
  const int bb = bh >> 4, h = bh & 15;
  float* obase = attout + ((long)bb * N_ + qt*64 + r) * DIM_ + h*HD_ + q4*16;
#pragma unroll
  for (int i4 = 0; i4 < 4; ++i4) {
    float4 val = make_float4(o[i4*4]*inv, o[i4*4+1]*inv, o[i4*4+2]*inv, o[i4*4+3]*inv);
    *(float4*)(obase + i4*4) = val;
  }
}

extern "C" void kernel_launch(void* const* d_in, const int* in_sizes, int n_in,
                              void* d_out, int out_size, void* d_ws, size_t ws_size,
                              hipStream_t stream) {
  const float* x     = (const float*)d_in[0];
  const float* Wqkv  = (const float*)d_in[1];
  const float* Wproj = (const float*)d_in[2];
  const float* bproj = (const float*)d_in[3];
  float* out = (float*)d_out;
  float* ws  = (float*)d_ws;
  float* q      = ws;                         // 8388608
  float* k      = q + QKV_SZ;                 // 8388608
  float* v      = k + QKV_SZ;                 // 8388608
  float* attout = v + QKV_SZ;                 // 8388608
  float* cs     = attout + (long)M_TOT*DIM_;  // 256
  float* sn     = cs + 256;                   // 256

  hipLaunchKernelGGL(qkv_gemm_k,  dim3(48, 128), dim3(256), 0, stream, x, Wqkv, q, k, v);
  hipLaunchKernelGGL(rope_table_k, dim3(1),      dim3(256), 0, stream, cs, sn);
  hipLaunchKernelGGL(rope_apply_k, dim3(16384),  dim3(256), 0, stream, q, k, cs, sn);
  hipLaunchKernelGGL(attn_k,       dim3(16, 128), dim3(256), 0, stream, q, k, v, attout);
  hipLaunchKernelGGL(proj_gemm_k,  dim3(16, 128), dim3(256), 0, stream, attout, Wproj, bproj, out);
}

// Round 2
// 1102.609 us; speedup vs baseline: 1.9277x; 1.9277x over previous
//
#include <hip/hip_runtime.h>
#include <math.h>

#define DIM_ 1024
#define HEADS_ 16
#define HD_ 64
#define B_ 8
#define N_ 1024
#define M_TOT 8192
#define QKV_SZ (B_*HEADS_*N_*HD_)   // 8388608 elements per (b,h,n,d) array

typedef __attribute__((ext_vector_type(8))) short v8s;    // 8 bf16 (4 VGPRs)
typedef __attribute__((ext_vector_type(4))) float f32x4;  // MFMA C/D

static __device__ __forceinline__ unsigned short f2bf(float x) {
  unsigned u = __float_as_uint(x);
  u += 0x7FFFu + ((u >> 16) & 1u);          // RNE
  return (unsigned short)(u >> 16);
}
static __device__ __forceinline__ float bf2f(unsigned short h) {
  return __uint_as_float(((unsigned)h) << 16);
}

// ---------------- RoPE table (fp64; angles reach ~1608 rad) ------------------
__global__ void rope_table_k(float* cs, float* sn) {
  int i = threadIdx.x;
  if (i < 256) {
    int pos = i >> 3, j = i & 7;
    double u = -1.0 + (double)pos * (2.0/31.0);
    double ang = u * ((1.0 + 73.0*(double)j) * 3.14159265358979323846);
    cs[i] = (float)cos(ang);
    sn[i] = (float)sin(ang);
  }
}

// ---------------- QKV GEMM (fp32) + fused RoPE + bf16 hi/lo split ------------
// q,k written as bf16 hi/lo (b,h,n,d) with q pre-scaled by 1/8; v written fp32.
__global__ __launch_bounds__(256) void qkv_gemm_k(const float* __restrict__ A,
                                                  const float* __restrict__ W,
                                                  const float* __restrict__ cs,
                                                  const float* __restrict__ sn,
                                                  unsigned short* __restrict__ qh,
                                                  unsigned short* __restrict__ ql,
                                                  unsigned short* __restrict__ kh,
                                                  unsigned short* __restrict__ kl,
                                                  float* __restrict__ v) {
  __shared__ float As[16][68];
  __shared__ float Bs[16][68];
  const int tid = threadIdx.x;
  const int m0 = blockIdx.y * 64;
  const int f0 = blockIdx.x * 64;
  const int tx = tid & 15, ty = tid >> 4;
  const int lr = tid >> 2, lc = (tid & 3) * 4;
  float acc[4][4] = {};
  const float* Aptr = A + (long)(m0 + lr) * DIM_ + lc;
  const float* Wptr = W + (long)(f0 + lr) * DIM_ + lc;
  for (int k0 = 0; k0 < DIM_; k0 += 16) {
    float4 av = *(const float4*)(Aptr + k0);
    float4 bv = *(const float4*)(Wptr + k0);
    As[lc+0][lr]=av.x; As[lc+1][lr]=av.y; As[lc+2][lr]=av.z; As[lc+3][lr]=av.w;
    Bs[lc+0][lr]=bv.x; Bs[lc+1][lr]=bv.y; Bs[lc+2][lr]=bv.z; Bs[lc+3][lr]=bv.w;
    __syncthreads();
#pragma unroll
    for (int kk = 0; kk < 16; ++kk) {
      float4 a4 = *(const float4*)&As[kk][ty*4];
      float4 b4 = *(const float4*)&Bs[kk][tx*4];
      float a[4] = {a4.x, a4.y, a4.z, a4.w};
      float b[4] = {b4.x, b4.y, b4.z, b4.w};
#pragma unroll
      for (int i = 0; i < 4; ++i)
#pragma unroll
        for (int j = 0; j < 4; ++j) acc[i][j] = fmaf(a[i], b[j], acc[i][j]);
    }
    __syncthreads();
  }
  const int qsel = f0 >> 10;             // 0=q 1=k 2=v (block-uniform)
  const int h = (f0 & 1023) >> 6;
  if (qsel == 2) {
#pragma unroll
    for (int i = 0; i < 4; ++i) {
      int m = m0 + ty*4 + i;
      int bb = m >> 10, n = m & 1023;
      float4 val = make_float4(acc[i][0], acc[i][1], acc[i][2], acc[i][3]);
      *(float4*)(v + ((size_t)(bb*HEADS_ + h)*N_ + n)*HD_ + tx*4) = val;
    }
    return;
  }
  // stage rope tables into LDS (As is dead; loop ended with a barrier)
  float* flat = &As[0][0];
  flat[tid] = cs[tid];
  flat[256 + tid] = sn[tid];
  __syncthreads();
  const float scale = (qsel == 0) ? 0.125f : 1.0f;
  unsigned short* oh = qsel ? kh : qh;
  unsigned short* ol = qsel ? kl : ql;
#pragma unroll
  for (int i = 0; i < 4; ++i) {
    int m = m0 + ty*4 + i;
    int bb = m >> 10, n = m & 1023;
    float x0 = acc[i][0]*scale, x1 = acc[i][1]*scale;
    float x2 = acc[i][2]*scale, x3 = acc[i][3]*scale;
    if (tx < 8) {   // d = tx*4..tx*4+3 < 32 -> rotated pairs (2tx, 2tx+1)
      int pp0 = tx*2, pp1 = tx*2 + 1;
      int pos0 = (pp0 < 8) ? (n >> 5) : (n & 31);
      float c0 = flat[pos0*8 + (pp0 & 7)], s0 = flat[256 + pos0*8 + (pp0 & 7)];
      int pos1 = (pp1 < 8) ? (n >> 5) : (n & 31);
      float c1 = flat[pos1*8 + (pp1 & 7)], s1 = flat[256 + pos1*8 + (pp1 & 7)];
      float r0 = x0*c0 - x1*s0, r1 = x1*c0 + x0*s0;
      float r2 = x2*c1 - x3*s1, r3 = x3*c1 + x2*s1;
      x0 = r0; x1 = r1; x2 = r2; x3 = r3;
    }
    unsigned short h0 = f2bf(x0), h1 = f2bf(x1), h2 = f2bf(x2), h3 = f2bf(x3);
    size_t off = ((size_t)(bb*HEADS_ + h)*N_ + n)*HD_ + tx*4;
    *(ushort4*)(oh + off) = make_ushort4(h0, h1, h2, h3);
    *(ushort4*)(ol + off) = make_ushort4(f2bf(x0 - bf2f(h0)), f2bf(x1 - bf2f(h1)),
                                         f2bf(x2 - bf2f(h2)), f2bf(x3 - bf2f(h3)));
  }
}

// ---------------- V transpose + bf16 hi/lo split: (bh,n,d) -> (bh,d,n) -------
__global__ __launch_bounds__(256) void vt_split_k(const float* __restrict__ v,
                                                  unsigned short* __restrict__ vth,
                                                  unsigned short* __restrict__ vtl) {
  __shared__ float T[64][65];
  const int tid = threadIdx.x;
  const int nt = blockIdx.x, bh = blockIdx.y;
  {
    const int nr = tid >> 2, dc = (tid & 3) * 16;
    const float* src = v + ((size_t)(bh*N_ + nt*64 + nr))*HD_ + dc;
#pragma unroll
    for (int i = 0; i < 4; ++i) {
      float4 t4 = *(const float4*)(src + i*4);
      T[nr][dc + i*4 + 0] = t4.x;
      T[nr][dc + i*4 + 1] = t4.y;
      T[nr][dc + i*4 + 2] = t4.z;
      T[nr][dc + i*4 + 3] = t4.w;
    }
  }
  __syncthreads();
  const int d = tid >> 2, nb = (tid & 3) * 16;
  __align__(16) unsigned short hh[16];
  __align__(16) unsigned short ll[16];
#pragma unroll
  for (int j = 0; j < 16; ++j) {
    float x = T[nb + j][d];
    unsigned short hb = f2bf(x);
    hh[j] = hb;
    ll[j] = f2bf(x - bf2f(hb));
  }
  size_t off = ((size_t)(bh*HD_ + d))*N_ + nt*64 + nb;
  *(uint4*)(vth + off)     = *(const uint4*)&hh[0];
  *(uint4*)(vth + off + 8) = *(const uint4*)&hh[8];
  *(uint4*)(vtl + off)     = *(const uint4*)&ll[0];
  *(uint4*)(vtl + off + 8) = *(const uint4*)&ll[8];
}

// ---------------- Flash attention, split-bf16 MFMA ---------------------------
// Block = (qt, bh): 64 q-rows, 4 waves x 16 rows. KV tiles of 64, 16 steps.
// K and V^T staged in LDS (bf16 hi/lo) with XOR swizzle (row&7)<<4.
__global__ __launch_bounds__(256) void attn_mfma_k(
    const unsigned short* __restrict__ qh, const unsigned short* __restrict__ ql,
    const unsigned short* __restrict__ kh, const unsigned short* __restrict__ kl,
    const unsigned short* __restrict__ vth, const unsigned short* __restrict__ vtl,
    float* __restrict__ attout) {
  __shared__ __align__(16) unsigned short KhS[4096], KlS[4096], VhS[4096], VlS[4096];
  __shared__ __align__(16) float Pws[4][16][68];
  const int tid = threadIdx.x;
  const int w = tid >> 6, l = tid & 63;
  const int lg = l >> 4, lc = l & 15;
  const int qt = blockIdx.x, bh = blockIdx.y;

  // Q fragments in registers: row = lc, k-slots (lg*8 + j) + 32c; q pre-scaled by 1/8
  v8s qfh[2], qfl[2];
  {
    const size_t qrow = ((size_t)bh*N_ + qt*64 + w*16 + lc) * HD_ + lg*8;
    qfh[0] = *(const v8s*)(qh + qrow);      qfh[1] = *(const v8s*)(qh + qrow + 32);
    qfl[0] = *(const v8s*)(ql + qrow);      qfl[1] = *(const v8s*)(ql + qrow + 32);
  }
  f32x4 O[4];
#pragma unroll
  for (int i = 0; i < 4; ++i) O[i] = (f32x4){0.f, 0.f, 0.f, 0.f};
  float mrow[4] = {-INFINITY, -INFINITY, -INFINITY, -INFINITY};
  float lrow[4] = {0.f, 0.f, 0.f, 0.f};

  const int srow = tid >> 2;                 // staging: row 0..63
  const int sb0  = (tid & 3) * 32;           // byte-in-row 0/32/64/96
  const int sswz = (srow & 7) << 4;
  const size_t kgb = (size_t)bh * N_ * HD_;  // kh/kl base (rows = n)
  const size_t vgb = (size_t)bh * HD_ * N_;  // vth/vtl base (rows = d)

  for (int t = 0; t < 16; ++t) {
    { // ---- stage K tile (64 keys x 64 d) and Vt tile (64 d x 64 keys)
      const char* gKh = (const char*)(kh + kgb + (size_t)(t*64 + srow)*HD_);
      const char* gKl = (const char*)(kl + kgb + (size_t)(t*64 + srow)*HD_);
      const char* gVh = (const char*)(vth + vgb + (size_t)srow*N_ + t*64);
      const char* gVl = (const char*)(vtl + vgb + (size_t)srow*N_ + t*64);
#pragma unroll
      for (int i = 0; i < 2; ++i) {
        const int b = sb0 + i*16;
        const int lo = srow*128 + (b ^ sswz);
        uint4 a0 = *(const uint4*)(gKh + b);
        uint4 a1 = *(const uint4*)(gKl + b);
        uint4 a2 = *(const uint4*)(gVh + b);
        uint4 a3 = *(const uint4*)(gVl + b);
        *(uint4*)((char*)KhS + lo) = a0;
        *(uint4*)((char*)KlS + lo) = a1;
        *(uint4*)((char*)VhS + lo) = a2;
        *(uint4*)((char*)VlS + lo) = a3;
      }
    }
    __syncthreads();
    // ---- QK^T: S tiles (16 q x 16 keys), key = kt*16 + lc
    f32x4 s[4];
#pragma unroll
    for (int kt = 0; kt < 4; ++kt) {
      s[kt] = (f32x4){0.f, 0.f, 0.f, 0.f};
      const int row = kt*16 + lc;
      const int sw = (row & 7) << 4;
#pragma unroll
      for (int c = 0; c < 2; ++c) {
        const int boff = row*128 + ((lg*16 + c*64) ^ sw);
        v8s kfh = *(const v8s*)((const char*)KhS + boff);
        v8s kfl = *(const v8s*)((const char*)KlS + boff);
        s[kt] = __builtin_amdgcn_mfma_f32_16x16x32_bf16(qfh[c], kfh, s[kt], 0, 0, 0);
        s[kt] = __builtin_amdgcn_mfma_f32_16x16x32_bf16(qfl[c], kfh, s[kt], 0, 0, 0);
        s[kt] = __builtin_amdgcn_mfma_f32_16x16x32_bf16(qfh[c], kfl, s[kt], 0, 0, 0);
      }
    }
    // ---- online softmax (rows r: q-row = lg*4 + r; cols across 16-lane group)
    float tmax[4], corr[4], psum[4];
#pragma unroll
    for (int r = 0; r < 4; ++r)
      tmax[r] = fmaxf(fmaxf(s[0][r], s[1][r]), fmaxf(s[2][r], s[3][r]));
#pragma unroll
    for (int r = 0; r < 4; ++r) {
      tmax[r] = fmaxf(tmax[r], __shfl_xor(tmax[r], 1));
      tmax[r] = fmaxf(tmax[r], __shfl_xor(tmax[r], 2));
      tmax[r] = fmaxf(tmax[r], __shfl_xor(tmax[r], 4));
      tmax[r] = fmaxf(tmax[r], __shfl_xor(tmax[r], 8));
    }
#pragma unroll
    for (int r = 0; r < 4; ++r) {
      float mn = fmaxf(mrow[r], tmax[r]);
      corr[r] = __expf(mrow[r] - mn);
      mrow[r] = mn;
      float ps = 0.f;
#pragma unroll
      for (int kt = 0; kt < 4; ++kt) {
        float pv = __expf(s[kt][r] - mn);
        s[kt][r] = pv;
        ps += pv;
      }
      psum[r] = ps;
    }
#pragma unroll
    for (int r = 0; r < 4; ++r) {
      float ps = psum[r];
      ps += __shfl_xor(ps, 1);
      ps += __shfl_xor(ps, 2);
      ps += __shfl_xor(ps, 4);
      ps += __shfl_xor(ps, 8);
      lrow[r] = lrow[r]*corr[r] + ps;
    }
#pragma unroll
    for (int dt = 0; dt < 4; ++dt)
#pragma unroll
      for (int r = 0; r < 4; ++r) O[dt][r] *= corr[r];
    // ---- P through per-wave LDS to re-fragment for PV
#pragma unroll
    for (int kt = 0; kt < 4; ++kt)
#pragma unroll
      for (int r = 0; r < 4; ++r)
        Pws[w][lg*4 + r][lc + kt*16] = s[kt][r];
    union { v8s v; unsigned short u[8]; } pah[2], pal[2];
#pragma unroll
    for (int c = 0; c < 2; ++c) {
      f32x4 p0 = *(const f32x4*)&Pws[w][lc][lg*8 + c*32];
      f32x4 p1 = *(const f32x4*)&Pws[w][lc][lg*8 + c*32 + 4];
#pragma unroll
      for (int j = 0; j < 4; ++j) {
        unsigned short hb0 = f2bf(p0[j]);
        pah[c].u[j] = hb0;  pal[c].u[j] = f2bf(p0[j] - bf2f(hb0));
        unsigned short hb1 = f2bf(p1[j]);
        pah[c].u[4+j] = hb1;  pal[c].u[4+j] = f2bf(p1[j] - bf2f(hb1));
      }
    }
    // ---- PV: O[dt] += P * V  (B-frag from Vt rows: d = dt*16 + lc)
#pragma unroll
    for (int dt = 0; dt < 4; ++dt) {
      const int row = dt*16 + lc;
      const int sw = (row & 7) << 4;
#pragma unroll
      for (int c = 0; c < 2; ++c) {
        const int boff = row*128 + ((lg*16 + c*64) ^ sw);
        v8s vfh = *(const v8s*)((const char*)VhS + boff);
        v8s vfl = *(const v8s*)((const char*)VlS + boff);
        O[dt] = __builtin_amdgcn_mfma_f32_16x16x32_bf16(pah[c].v, vfh, O[dt], 0, 0, 0);
        O[dt] = __builtin_amdgcn_mfma_f32_16x16x32_bf16(pal[c].v, vfh, O[dt], 0, 0, 0);
        O[dt] = __builtin_amdgcn_mfma_f32_16x16x32_bf16(pah[c].v, vfl, O[dt], 0, 0, 0);
      }
    }
    __syncthreads();   // all waves done reading tiles before next stage
  }
  // ---- epilogue: attout (B, N, DIM) fp32
  const int b = bh >> 4, h = bh & 15;
#pragma unroll
  for (int r = 0; r < 4; ++r) {
    float inv = 1.0f / lrow[r];
    const int n = qt*64 + w*16 + lg*4 + r;
    float* op = attout + ((size_t)(b*N_ + n))*DIM_ + h*HD_ + lc;
#pragma unroll
    for (int dt = 0; dt < 4; ++dt) op[dt*16] = O[dt][r] * inv;
  }
}

// ---------------- Proj GEMM (fp32): out = att * Wproj^T + bias ---------------
__global__ __launch_bounds__(256) void proj_gemm_k(const float* __restrict__ A,
                                                   const float* __restrict__ W,
                                                   const float* __restrict__ bias,
                                                   float* __restrict__ out) {
  __shared__ float As[16][68];
  __shared__ float Bs[16][68];
  const int tid = threadIdx.x;
  const int m0 = blockIdx.y * 64;
  const int o0 = blockIdx.x * 64;
  const int tx = tid & 15, ty = tid >> 4;
  const int lr = tid >> 2, lc = (tid & 3) * 4;
  float acc[4][4] = {};
  const float* Aptr = A + (long)(m0 + lr) * DIM_ + lc;
  const float* Wptr = W + (long)(o0 + lr) * DIM_ + lc;
  for (int k0 = 0; k0 < DIM_; k0 += 16) {
    float4 av = *(const float4*)(Aptr + k0);
    float4 bv = *(const float4*)(Wptr + k0);
    As[lc+0][lr]=av.x; As[lc+1][lr]=av.y; As[lc+2][lr]=av.z; As[lc+3][lr]=av.w;
    Bs[lc+0][lr]=bv.x; Bs[lc+1][lr]=bv.y; Bs[lc+2][lr]=bv.z; Bs[lc+3][lr]=bv.w;
    __syncthreads();
#pragma unroll
    for (int kk = 0; kk < 16; ++kk) {
      float4 a4 = *(const float4*)&As[kk][ty*4];
      float4 b4 = *(const float4*)&Bs[kk][tx*4];
      float a[4] = {a4.x, a4.y, a4.z, a4.w};
      float b[4] = {b4.x, b4.y, b4.z, b4.w};
#pragma unroll
      for (int i = 0; i < 4; ++i)
#pragma unroll
        for (int j = 0; j < 4; ++j) acc[i][j] = fmaf(a[i], b[j], acc[i][j]);
    }
    __syncthreads();
  }
  float4 bv = *(const float4*)(bias + o0 + tx*4);
#pragma unroll
  for (int i = 0; i < 4; ++i) {
    int m = m0 + ty*4 + i;
    float4 val = make_float4(acc[i][0]+bv.x, acc[i][1]+bv.y, acc[i][2]+bv.z, acc[i][3]+bv.w);
    *(float4*)(out + (long)m*DIM_ + o0 + tx*4) = val;
  }
}

extern "C" void kernel_launch(void* const* d_in, const int* in_sizes, int n_in,
                              void* d_out, int out_size, void* d_ws, size_t ws_size,
                              hipStream_t stream) {
  const float* x     = (const float*)d_in[0];
  const float* Wqkv  = (const float*)d_in[1];
  const float* Wproj = (const float*)d_in[2];
  const float* bproj = (const float*)d_in[3];
  float* out = (float*)d_out;
  float* ws  = (float*)d_ws;

  float* v      = ws;                                      // 8.4M f32
  float* attout = v + QKV_SZ;                              // 8.4M f32
  unsigned short* qh  = (unsigned short*)(attout + QKV_SZ);
  unsigned short* ql  = qh + QKV_SZ;
  unsigned short* kh  = ql + QKV_SZ;
  unsigned short* kl  = kh + QKV_SZ;
  unsigned short* vth = kl + QKV_SZ;
  unsigned short* vtl = vth + QKV_SZ;
  float* cs = (float*)(vtl + QKV_SZ);
  float* sn = cs + 256;

  hipLaunchKernelGGL(rope_table_k, dim3(1),        dim3(256), 0, stream, cs, sn);
  hipLaunchKernelGGL(qkv_gemm_k,   dim3(48, 128),  dim3(256), 0, stream,
                     x, Wqkv, cs, sn, qh, ql, kh, kl, v);
  hipLaunchKernelGGL(vt_split_k,   dim3(16, 128),  dim3(256), 0, stream, v, vth, vtl);
  hipLaunchKernelGGL(attn_mfma_k,  dim3(16, 128),  dim3(256), 0, stream,
                     qh, ql, kh, kl, vth, vtl, attout);
  hipLaunchKernelGGL(proj_gemm_k,  dim3(16, 128),  dim3(256), 0, stream,
                     attout, Wproj, bproj, out);
}

// Round 3
// 417.911 us; speedup vs baseline: 5.0860x; 2.6384x over previous
//
#include <hip/hip_runtime.h>
#include <math.h>

#define DIM_ 1024
#define HEADS_ 16
#define HD_ 64
#define B_ 8
#define N_ 1024
#define M_TOT 8192
#define QKV_SZ (B_*HEADS_*N_*HD_)   // 8388608 elements per (b,h,n,d) array

typedef __attribute__((ext_vector_type(8))) short v8s;    // 8 bf16 (4 VGPRs)
typedef __attribute__((ext_vector_type(4))) float f32x4;  // MFMA C/D

static __device__ __forceinline__ unsigned short f2bf(float x) {
  unsigned u = __float_as_uint(x);
  u += 0x7FFFu + ((u >> 16) & 1u);          // RNE
  return (unsigned short)(u >> 16);
}
static __device__ __forceinline__ float bf2f(unsigned short h) {
  return __uint_as_float(((unsigned)h) << 16);
}

static __device__ __forceinline__ void gload16(unsigned short* lds_base,
                                               const unsigned short* g) {
  __builtin_amdgcn_global_load_lds(
      (const __attribute__((address_space(1))) unsigned int*)g,
      (__attribute__((address_space(3))) unsigned int*)lds_base, 16, 0, 0);
}

// ---------------- fp32 -> bf16 hi/lo split (vectorized) ----------------------
__global__ __launch_bounds__(256) void split_k(const float* __restrict__ src,
                                               unsigned short* __restrict__ hi,
                                               unsigned short* __restrict__ lo,
                                               int n4) {
  int i = blockIdx.x * 256 + threadIdx.x;
  if (i >= n4) return;
  float4 x = ((const float4*)src)[i];
  ushort4 h, l;
  h.x = f2bf(x.x); l.x = f2bf(x.x - bf2f(h.x));
  h.y = f2bf(x.y); l.y = f2bf(x.y - bf2f(h.y));
  h.z = f2bf(x.z); l.z = f2bf(x.z - bf2f(h.z));
  h.w = f2bf(x.w); l.w = f2bf(x.w - bf2f(h.w));
  ((ushort4*)hi)[i] = h;
  ((ushort4*)lo)[i] = l;
}

// ---------------- RoPE table (fp64; angles reach ~1608 rad) ------------------
__global__ void rope_table_k(float* cs, float* sn) {
  int i = threadIdx.x;
  if (i < 256) {
    int pos = i >> 3, j = i & 7;
    double u = -1.0 + (double)pos * (2.0/31.0);
    double ang = u * ((1.0 + 73.0*(double)j) * 3.14159265358979323846);
    cs[i] = (float)cos(ang);
    sn[i] = (float)sin(ang);
  }
}

// ---------------- shared split-bf16 MFMA GEMM core ---------------------------
// C[m,f] = A[m,:]·B[f,:], A/B given as bf16 hi/lo row-major [.][1024].
// 128x128 tile, BK=32, 4 waves 2x2, per-wave 4x4 16x16 fragments.
// LDS row = 128B: [hi chunks 0..3 | lo chunks 0..3], 16B chunks XOR-swizzled
// by ((row&7)<<4); swizzle applied on the GLOBAL side (linear global_load_lds).
static __device__ __forceinline__ void gemm_core(
    const unsigned short* __restrict__ ah, const unsigned short* __restrict__ al,
    const unsigned short* __restrict__ bh, const unsigned short* __restrict__ bl,
    unsigned short* AS, unsigned short* BS,
    int m0, int f0, f32x4 acc[4][4]) {
  const int tid = threadIdx.x;
  const int w = tid >> 6, l = tid & 63;
  const int lg = l >> 4, lc = l & 15;
  const int wr = w >> 1, wc = w & 1;
  const int srow = l >> 3;            // 0..7 within staging instruction
  const int cc = (l & 7) ^ srow;      // pre-swizzled source chunk
  const int kc = (cc & 3) * 8;        // k offset of chunk (elements)
  for (int k0 = 0; k0 < 1024; k0 += 32) {
#pragma unroll
    for (int i = 0; i < 4; ++i) {
      const int j = w*4 + i;
      const int row = j*8 + srow;
      const unsigned short* sA = (cc < 4 ? ah : al) + (size_t)(m0 + row)*1024 + k0 + kc;
      const unsigned short* sB = (cc < 4 ? bh : bl) + (size_t)(f0 + row)*1024 + k0 + kc;
      gload16(AS + j*512, sA);
      gload16(BS + j*512, sB);
    }
    __syncthreads();
    v8s a_h[4], a_l[4], b_h[4], b_l[4];
#pragma unroll
    for (int mi = 0; mi < 4; ++mi) {
      const int row = wr*64 + mi*16 + lc;
      const char* base = (const char*)AS + row*128;
      const int sw = (row & 7) << 4;
      a_h[mi] = *(const v8s*)(base + ((lg*16) ^ sw));
      a_l[mi] = *(const v8s*)(base + ((64 + lg*16) ^ sw));
    }
#pragma unroll
    for (int nj = 0; nj < 4; ++nj) {
      const int row = wc*64 + nj*16 + lc;
      const char* base = (const char*)BS + row*128;
      const int sw = (row & 7) << 4;
      b_h[nj] = *(const v8s*)(base + ((lg*16) ^ sw));
      b_l[nj] = *(const v8s*)(base + ((64 + lg*16) ^ sw));
    }
#pragma unroll
    for (int mi = 0; mi < 4; ++mi)
#pragma unroll
      for (int nj = 0; nj < 4; ++nj) {
        acc[mi][nj] = __builtin_amdgcn_mfma_f32_16x16x32_bf16(a_h[mi], b_h[nj], acc[mi][nj], 0, 0, 0);
        acc[mi][nj] = __builtin_amdgcn_mfma_f32_16x16x32_bf16(a_l[mi], b_h[nj], acc[mi][nj], 0, 0, 0);
        acc[mi][nj] = __builtin_amdgcn_mfma_f32_16x16x32_bf16(a_h[mi], b_l[nj], acc[mi][nj], 0, 0, 0);
      }
    __syncthreads();
  }
}

// ---------------- QKV GEMM (MFMA) + fused RoPE + hi/lo outputs ---------------
__global__ __launch_bounds__(256) void qkv_gemm_mfma(
    const unsigned short* __restrict__ xh, const unsigned short* __restrict__ xl,
    const unsigned short* __restrict__ wh, const unsigned short* __restrict__ wl,
    const float* __restrict__ cs, const float* __restrict__ sn,
    unsigned short* __restrict__ qh, unsigned short* __restrict__ ql,
    unsigned short* __restrict__ kh, unsigned short* __restrict__ kl,
    float* __restrict__ vout) {
  __shared__ unsigned short AS[8192];
  __shared__ unsigned short BS[8192];
  const int tid = threadIdx.x;
  const int w = tid >> 6, l = tid & 63;
  const int lg = l >> 4, lc = l & 15;
  const int wr = w >> 1, wc = w & 1;
  // bijective XCD swizzle (nwg = 1536, divisible by 8)
  const int nwg = gridDim.x * gridDim.y;
  int bid = blockIdx.y * gridDim.x + blockIdx.x;
  bid = (bid & 7) * (nwg >> 3) + (bid >> 3);
  const int m0 = (bid / gridDim.x) * 128;
  const int f0 = (bid % gridDim.x) * 128;
  f32x4 acc[4][4] = {};
  gemm_core(xh, xl, wh, wl, AS, BS, m0, f0, acc);
  const int qsel = f0 >> 10;                 // block-uniform (128 | 1024)
  const int head = ((f0 & 1023) >> 6) + wc;  // wave-uniform head
  if (qsel == 2) {
#pragma unroll
    for (int mi = 0; mi < 4; ++mi)
#pragma unroll
      for (int nj = 0; nj < 4; ++nj)
#pragma unroll
        for (int r = 0; r < 4; ++r) {
          const int m = m0 + wr*64 + mi*16 + lg*4 + r;
          const int b = m >> 10, n = m & 1023;
          vout[((size_t)(b*HEADS_ + head)*N_ + n)*HD_ + nj*16 + lc] = acc[mi][nj][r];
        }
    return;
  }
  // stage rope tables into LDS (core ended on a barrier; AS is dead)
  float* tbl = (float*)AS;
  tbl[tid] = cs[tid];
  tbl[256 + tid] = sn[tid];
  __syncthreads();
  const float scale = (qsel == 0) ? 0.125f : 1.0f;
  unsigned short* oh = qsel ? kh : qh;
  unsigned short* ol = qsel ? kl : ql;
#pragma unroll
  for (int mi = 0; mi < 4; ++mi)
#pragma unroll
    for (int nj = 0; nj < 4; ++nj) {
      const int d = nj*16 + lc;
#pragma unroll
      for (int r = 0; r < 4; ++r) {
        const int m = m0 + wr*64 + mi*16 + lg*4 + r;
        const int b = m >> 10, n = m & 1023;
        float val = acc[mi][nj][r] * scale;
        float part = __shfl_xor(val, 1);
        if (nj < 2) {   // d < 32 -> rotated
          const int p = d >> 1;
          const int pos = (p < 8) ? (n >> 5) : (n & 31);
          const float c = tbl[pos*8 + (p & 7)];
          const float s = tbl[256 + pos*8 + (p & 7)];
          val = (d & 1) ? (val*c + part*s) : (val*c - part*s);
        }
        const unsigned short hb = f2bf(val);
        const size_t off = ((size_t)(b*HEADS_ + head)*N_ + n)*HD_ + d;
        oh[off] = hb;
        ol[off] = f2bf(val - bf2f(hb));
      }
    }
}

// ---------------- Proj GEMM (MFMA): out = att·Wproj^T + bias -----------------
__global__ __launch_bounds__(256) void proj_gemm_mfma(
    const unsigned short* __restrict__ ah, const unsigned short* __restrict__ al,
    const unsigned short* __restrict__ wh, const unsigned short* __restrict__ wl,
    const float* __restrict__ bias, float* __restrict__ out) {
  __shared__ unsigned short AS[8192];
  __shared__ unsigned short BS[8192];
  const int tid = threadIdx.x;
  const int w = tid >> 6, l = tid & 63;
  const int lg = l >> 4, lc = l & 15;
  const int wr = w >> 1, wc = w & 1;
  const int nwg = gridDim.x * gridDim.y;   // 512, divisible by 8
  int bid = blockIdx.y * gridDim.x + blockIdx.x;
  bid = (bid & 7) * (nwg >> 3) + (bid >> 3);
  const int m0 = (bid / gridDim.x) * 128;
  const int o0 = (bid % gridDim.x) * 128;
  f32x4 acc[4][4] = {};
  gemm_core(ah, al, wh, wl, AS, BS, m0, o0, acc);
#pragma unroll
  for (int nj = 0; nj < 4; ++nj) {
    const int o = o0 + wc*64 + nj*16 + lc;
    const float bv = bias[o];
#pragma unroll
    for (int mi = 0; mi < 4; ++mi)
#pragma unroll
      for (int r = 0; r < 4; ++r) {
        const int m = m0 + wr*64 + mi*16 + lg*4 + r;
        out[(size_t)m*DIM_ + o] = acc[mi][nj][r] + bv;
      }
  }
}

// ---------------- V transpose + bf16 hi/lo split: (bh,n,d) -> (bh,d,n) -------
__global__ __launch_bounds__(256) void vt_split_k(const float* __restrict__ v,
                                                  unsigned short* __restrict__ vth,
                                                  unsigned short* __restrict__ vtl) {
  __shared__ float T[64][65];
  const int tid = threadIdx.x;
  const int nt = blockIdx.x, bh = blockIdx.y;
  {
    const int nr = tid >> 2, dc = (tid & 3) * 16;
    const float* src = v + ((size_t)(bh*N_ + nt*64 + nr))*HD_ + dc;
#pragma unroll
    for (int i = 0; i < 4; ++i) {
      float4 t4 = *(const float4*)(src + i*4);
      T[nr][dc + i*4 + 0] = t4.x;
      T[nr][dc + i*4 + 1] = t4.y;
      T[nr][dc + i*4 + 2] = t4.z;
      T[nr][dc + i*4 + 3] = t4.w;
    }
  }
  __syncthreads();
  const int d = tid >> 2, nb = (tid & 3) * 16;
  __align__(16) unsigned short hh[16];
  __align__(16) unsigned short ll[16];
#pragma unroll
  for (int j = 0; j < 16; ++j) {
    float x = T[nb + j][d];
    unsigned short hb = f2bf(x);
    hh[j] = hb;
    ll[j] = f2bf(x - bf2f(hb));
  }
  size_t off = ((size_t)(bh*HD_ + d))*N_ + nt*64 + nb;
  *(uint4*)(vth + off)     = *(const uint4*)&hh[0];
  *(uint4*)(vth + off + 8) = *(const uint4*)&hh[8];
  *(uint4*)(vtl + off)     = *(const uint4*)&ll[0];
  *(uint4*)(vtl + off + 8) = *(const uint4*)&ll[8];
}

// ---------------- Flash attention, split-bf16 MFMA ---------------------------
__global__ __launch_bounds__(256) void attn_mfma_k(
    const unsigned short* __restrict__ qh, const unsigned short* __restrict__ ql,
    const unsigned short* __restrict__ kh, const unsigned short* __restrict__ kl,
    const unsigned short* __restrict__ vth, const unsigned short* __restrict__ vtl,
    unsigned short* __restrict__ aoh, unsigned short* __restrict__ aol) {
  __shared__ __align__(16) unsigned short KhS[4096], KlS[4096], VhS[4096], VlS[4096];
  __shared__ __align__(16) float Pws[4][16][68];
  const int tid = threadIdx.x;
  const int w = tid >> 6, l = tid & 63;
  const int lg = l >> 4, lc = l & 15;
  const int qt = blockIdx.x, bh = blockIdx.y;

  v8s qfh[2], qfl[2];
  {
    const size_t qrow = ((size_t)bh*N_ + qt*64 + w*16 + lc) * HD_ + lg*8;
    qfh[0] = *(const v8s*)(qh + qrow);      qfh[1] = *(const v8s*)(qh + qrow + 32);
    qfl[0] = *(const v8s*)(ql + qrow);      qfl[1] = *(const v8s*)(ql + qrow + 32);
  }
  f32x4 O[4];
#pragma unroll
  for (int i = 0; i < 4; ++i) O[i] = (f32x4){0.f, 0.f, 0.f, 0.f};
  float mrow[4] = {-INFINITY, -INFINITY, -INFINITY, -INFINITY};
  float lrow[4] = {0.f, 0.f, 0.f, 0.f};

  const int srow = tid >> 2;
  const int sb0  = (tid & 3) * 32;
  const int sswz = (srow & 7) << 4;
  const size_t kgb = (size_t)bh * N_ * HD_;
  const size_t vgb = (size_t)bh * HD_ * N_;

  for (int t = 0; t < 16; ++t) {
    {
      const char* gKh = (const char*)(kh + kgb + (size_t)(t*64 + srow)*HD_);
      const char* gKl = (const char*)(kl + kgb + (size_t)(t*64 + srow)*HD_);
      const char* gVh = (const char*)(vth + vgb + (size_t)srow*N_ + t*64);
      const char* gVl = (const char*)(vtl + vgb + (size_t)srow*N_ + t*64);
#pragma unroll
      for (int i = 0; i < 2; ++i) {
        const int b = sb0 + i*16;
        const int lo = srow*128 + (b ^ sswz);
        uint4 a0 = *(const uint4*)(gKh + b);
        uint4 a1 = *(const uint4*)(gKl + b);
        uint4 a2 = *(const uint4*)(gVh + b);
        uint4 a3 = *(const uint4*)(gVl + b);
        *(uint4*)((char*)KhS + lo) = a0;
        *(uint4*)((char*)KlS + lo) = a1;
        *(uint4*)((char*)VhS + lo) = a2;
        *(uint4*)((char*)VlS + lo) = a3;
      }
    }
    __syncthreads();
    f32x4 s[4];
#pragma unroll
    for (int kt = 0; kt < 4; ++kt) {
      s[kt] = (f32x4){0.f, 0.f, 0.f, 0.f};
      const int row = kt*16 + lc;
      const int sw = (row & 7) << 4;
#pragma unroll
      for (int c = 0; c < 2; ++c) {
        const int boff = row*128 + ((lg*16 + c*64) ^ sw);
        v8s kfh = *(const v8s*)((const char*)KhS + boff);
        v8s kfl = *(const v8s*)((const char*)KlS + boff);
        s[kt] = __builtin_amdgcn_mfma_f32_16x16x32_bf16(qfh[c], kfh, s[kt], 0, 0, 0);
        s[kt] = __builtin_amdgcn_mfma_f32_16x16x32_bf16(qfl[c], kfh, s[kt], 0, 0, 0);
        s[kt] = __builtin_amdgcn_mfma_f32_16x16x32_bf16(qfh[c], kfl, s[kt], 0, 0, 0);
      }
    }
    float tmax[4], corr[4], psum[4];
#pragma unroll
    for (int r = 0; r < 4; ++r)
      tmax[r] = fmaxf(fmaxf(s[0][r], s[1][r]), fmaxf(s[2][r], s[3][r]));
#pragma unroll
    for (int r = 0; r < 4; ++r) {
      tmax[r] = fmaxf(tmax[r], __shfl_xor(tmax[r], 1));
      tmax[r] = fmaxf(tmax[r], __shfl_xor(tmax[r], 2));
      tmax[r] = fmaxf(tmax[r], __shfl_xor(tmax[r], 4));
      tmax[r] = fmaxf(tmax[r], __shfl_xor(tmax[r], 8));
    }
#pragma unroll
    for (int r = 0; r < 4; ++r) {
      float mn = fmaxf(mrow[r], tmax[r]);
      corr[r] = __expf(mrow[r] - mn);
      mrow[r] = mn;
      float ps = 0.f;
#pragma unroll
      for (int kt = 0; kt < 4; ++kt) {
        float pv = __expf(s[kt][r] - mn);
        s[kt][r] = pv;
        ps += pv;
      }
      psum[r] = ps;
    }
#pragma unroll
    for (int r = 0; r < 4; ++r) {
      float ps = psum[r];
      ps += __shfl_xor(ps, 1);
      ps += __shfl_xor(ps, 2);
      ps += __shfl_xor(ps, 4);
      ps += __shfl_xor(ps, 8);
      lrow[r] = lrow[r]*corr[r] + ps;
    }
#pragma unroll
    for (int dt = 0; dt < 4; ++dt)
#pragma unroll
      for (int r = 0; r < 4; ++r) O[dt][r] *= corr[r];
#pragma unroll
    for (int kt = 0; kt < 4; ++kt)
#pragma unroll
      for (int r = 0; r < 4; ++r)
        Pws[w][lg*4 + r][lc + kt*16] = s[kt][r];
    union { v8s v; unsigned short u[8]; } pah[2], pal[2];
#pragma unroll
    for (int c = 0; c < 2; ++c) {
      f32x4 p0 = *(const f32x4*)&Pws[w][lc][lg*8 + c*32];
      f32x4 p1 = *(const f32x4*)&Pws[w][lc][lg*8 + c*32 + 4];
#pragma unroll
      for (int j = 0; j < 4; ++j) {
        unsigned short hb0 = f2bf(p0[j]);
        pah[c].u[j] = hb0;  pal[c].u[j] = f2bf(p0[j] - bf2f(hb0));
        unsigned short hb1 = f2bf(p1[j]);
        pah[c].u[4+j] = hb1;  pal[c].u[4+j] = f2bf(p1[j] - bf2f(hb1));
      }
    }
#pragma unroll
    for (int dt = 0; dt < 4; ++dt) {
      const int row = dt*16 + lc;
      const int sw = (row & 7) << 4;
#pragma unroll
      for (int c = 0; c < 2; ++c) {
        const int boff = row*128 + ((lg*16 + c*64) ^ sw);
        v8s vfh = *(const v8s*)((const char*)VhS + boff);
        v8s vfl = *(const v8s*)((const char*)VlS + boff);
        O[dt] = __builtin_amdgcn_mfma_f32_16x16x32_bf16(pah[c].v, vfh, O[dt], 0, 0, 0);
        O[dt] = __builtin_amdgcn_mfma_f32_16x16x32_bf16(pal[c].v, vfh, O[dt], 0, 0, 0);
        O[dt] = __builtin_amdgcn_mfma_f32_16x16x32_bf16(pah[c].v, vfl, O[dt], 0, 0, 0);
      }
    }
    __syncthreads();
  }
  const int b = bh >> 4, h = bh & 15;
#pragma unroll
  for (int r = 0; r < 4; ++r) {
    const float inv = 1.0f / lrow[r];
    const int n = qt*64 + w*16 + lg*4 + r;
    const size_t base = ((size_t)(b*N_ + n))*DIM_ + h*HD_ + lc;
#pragma unroll
    for (int dt = 0; dt < 4; ++dt) {
      const float val = O[dt][r] * inv;
      const unsigned short hb = f2bf(val);
      aoh[base + dt*16] = hb;
      aol[base + dt*16] = f2bf(val - bf2f(hb));
    }
  }
}

extern "C" void kernel_launch(void* const* d_in, const int* in_sizes, int n_in,
                              void* d_out, int out_size, void* d_ws, size_t ws_size,
                              hipStream_t stream) {
  const float* x     = (const float*)d_in[0];
  const float* Wqkv  = (const float*)d_in[1];
  const float* Wproj = (const float*)d_in[2];
  const float* bproj = (const float*)d_in[3];
  float* out = (float*)d_out;

  unsigned short* xh  = (unsigned short*)d_ws;             // 8388608
  unsigned short* xl  = xh  + 8388608;                     // 8388608
  unsigned short* wqh = xl  + 8388608;                     // 3145728
  unsigned short* wql = wqh + 3145728;
  unsigned short* wph = wql + 3145728;                     // 1048576
  unsigned short* wpl = wph + 1048576;
  unsigned short* qh  = wpl + 1048576;                     // 8388608 x4
  unsigned short* ql  = qh  + 8388608;
  unsigned short* kh  = ql  + 8388608;
  unsigned short* kl  = kh  + 8388608;
  float* v  = (float*)(kl + 8388608);                      // 8388608 f32
  float* cs = v + 8388608;                                 // 256
  float* sn = cs + 256;                                    // 256
  // aliases (lifetimes disjoint): V^T lives where x-splits were; attout where v was
  unsigned short* vth = xh;
  unsigned short* vtl = xl;
  unsigned short* aoh = (unsigned short*)v;
  unsigned short* aol = aoh + 8388608;

  hipLaunchKernelGGL(rope_table_k, dim3(1), dim3(256), 0, stream, cs, sn);
  hipLaunchKernelGGL(split_k, dim3(8192), dim3(256), 0, stream, x,     xh,  xl,  2097152);
  hipLaunchKernelGGL(split_k, dim3(3072), dim3(256), 0, stream, Wqkv,  wqh, wql, 786432);
  hipLaunchKernelGGL(split_k, dim3(1024), dim3(256), 0, stream, Wproj, wph, wpl, 262144);
  hipLaunchKernelGGL(qkv_gemm_mfma, dim3(24, 64), dim3(256), 0, stream,
                     xh, xl, wqh, wql, cs, sn, qh, ql, kh, kl, v);
  hipLaunchKernelGGL(vt_split_k, dim3(16, 128), dim3(256), 0, stream, v, vth, vtl);
  hipLaunchKernelGGL(attn_mfma_k, dim3(16, 128), dim3(256), 0, stream,
                     qh, ql, kh, kl, vth, vtl, aoh, aol);
  hipLaunchKernelGGL(proj_gemm_mfma, dim3(8, 64), dim3(256), 0, stream,
                     aoh, aol, wph, wpl, bproj, out);
}

// Round 5
// 339.374 us; speedup vs baseline: 6.2629x; 1.2314x over previous
//
#include <hip/hip_runtime.h>
#include <math.h>

#define DIM_ 1024
#define HEADS_ 16
#define HD_ 64
#define B_ 8
#define N_ 1024
#define M_TOT 8192
#define QKV_SZ (B_*HEADS_*N_*HD_)   // 8388608 elements per (b,h,n,d) array

typedef __attribute__((ext_vector_type(8))) short v8s;    // 8 bf16
typedef __attribute__((ext_vector_type(4))) float f32x4;  // MFMA C/D
typedef _Float16 v8h __attribute__((ext_vector_type(8))); // 8 fp16
typedef __attribute__((ext_vector_type(4))) unsigned int u32x4;

static __device__ __forceinline__ unsigned short f2bf(float x) {
  unsigned u = __float_as_uint(x);
  u += 0x7FFFu + ((u >> 16) & 1u);          // RNE
  return (unsigned short)(u >> 16);
}
static __device__ __forceinline__ float bf2f(unsigned short h) {
  return __uint_as_float(((unsigned)h) << 16);
}
static __device__ __forceinline__ unsigned short f2h(float x) {
  _Float16 h = (_Float16)x;
  return __builtin_bit_cast(unsigned short, h);
}
static __device__ __forceinline__ float h2fl(unsigned short u) {
  return (float)__builtin_bit_cast(_Float16, u);
}
static __device__ __forceinline__ float fexp2(float x) {
  return __builtin_amdgcn_exp2f(x);
}
static __device__ __forceinline__ unsigned pkh2(float a, float b) {
  auto t = __builtin_amdgcn_cvt_pkrtz(a, b);   // __fp16 ext_vector(2), 4 bytes
  return __builtin_bit_cast(unsigned, t);
}

static __device__ __forceinline__ void gload16(unsigned short* lds_base,
                                               const unsigned short* g) {
  __builtin_amdgcn_global_load_lds(
      (const __attribute__((address_space(1))) unsigned int*)g,
      (__attribute__((address_space(3))) unsigned int*)lds_base, 16, 0, 0);
}

// ---------------- fp32 -> bf16 hi/lo split (vectorized) ----------------------
__global__ __launch_bounds__(256) void split_k(const float* __restrict__ src,
                                               unsigned short* __restrict__ hi,
                                               unsigned short* __restrict__ lo,
                                               int n4) {
  int i = blockIdx.x * 256 + threadIdx.x;
  if (i >= n4) return;
  float4 x = ((const float4*)src)[i];
  ushort4 h, l;
  h.x = f2bf(x.x); l.x = f2bf(x.x - bf2f(h.x));
  h.y = f2bf(x.y); l.y = f2bf(x.y - bf2f(h.y));
  h.z = f2bf(x.z); l.z = f2bf(x.z - bf2f(h.z));
  h.w = f2bf(x.w); l.w = f2bf(x.w - bf2f(h.w));
  ((ushort4*)hi)[i] = h;
  ((ushort4*)lo)[i] = l;
}

// ---------------- RoPE table (fp64; angles reach ~1608 rad) ------------------
__global__ void rope_table_k(float* cs, float* sn) {
  int i = threadIdx.x;
  if (i < 256) {
    int pos = i >> 3, j = i & 7;
    double u = -1.0 + (double)pos * (2.0/31.0);
    double ang = u * ((1.0 + 73.0*(double)j) * 3.14159265358979323846);
    cs[i] = (float)cos(ang);
    sn[i] = (float)sin(ang);
  }
}

// ---------------- shared split-bf16 MFMA GEMM core ---------------------------
static __device__ __forceinline__ void gemm_core(
    const unsigned short* __restrict__ ah, const unsigned short* __restrict__ al,
    const unsigned short* __restrict__ bh, const unsigned short* __restrict__ bl,
    unsigned short* AS, unsigned short* BS,
    int m0, int f0, f32x4 acc[4][4]) {
  const int tid = threadIdx.x;
  const int w = tid >> 6, l = tid & 63;
  const int lg = l >> 4, lc = l & 15;
  const int wr = w >> 1, wc = w & 1;
  const int srow = l >> 3;            // 0..7 within staging instruction
  const int cc = (l & 7) ^ srow;      // pre-swizzled source chunk
  const int kc = (cc & 3) * 8;        // k offset of chunk (elements)
  for (int k0 = 0; k0 < 1024; k0 += 32) {
#pragma unroll
    for (int i = 0; i < 4; ++i) {
      const int j = w*4 + i;
      const int row = j*8 + srow;
      const unsigned short* sA = (cc < 4 ? ah : al) + (size_t)(m0 + row)*1024 + k0 + kc;
      const unsigned short* sB = (cc < 4 ? bh : bl) + (size_t)(f0 + row)*1024 + k0 + kc;
      gload16(AS + j*512, sA);
      gload16(BS + j*512, sB);
    }
    __syncthreads();
    v8s a_h[4], a_l[4], b_h[4], b_l[4];
#pragma unroll
    for (int mi = 0; mi < 4; ++mi) {
      const int row = wr*64 + mi*16 + lc;
      const char* base = (const char*)AS + row*128;
      const int sw = (row & 7) << 4;
      a_h[mi] = *(const v8s*)(base + ((lg*16) ^ sw));
      a_l[mi] = *(const v8s*)(base + ((64 + lg*16) ^ sw));
    }
#pragma unroll
    for (int nj = 0; nj < 4; ++nj) {
      const int row = wc*64 + nj*16 + lc;
      const char* base = (const char*)BS + row*128;
      const int sw = (row & 7) << 4;
      b_h[nj] = *(const v8s*)(base + ((lg*16) ^ sw));
      b_l[nj] = *(const v8s*)(base + ((64 + lg*16) ^ sw));
    }
#pragma unroll
    for (int mi = 0; mi < 4; ++mi)
#pragma unroll
      for (int nj = 0; nj < 4; ++nj) {
        acc[mi][nj] = __builtin_amdgcn_mfma_f32_16x16x32_bf16(a_h[mi], b_h[nj], acc[mi][nj], 0, 0, 0);
        acc[mi][nj] = __builtin_amdgcn_mfma_f32_16x16x32_bf16(a_l[mi], b_h[nj], acc[mi][nj], 0, 0, 0);
        acc[mi][nj] = __builtin_amdgcn_mfma_f32_16x16x32_bf16(a_h[mi], b_l[nj], acc[mi][nj], 0, 0, 0);
      }
    __syncthreads();
  }
}

// ---------------- QKV GEMM (MFMA) + fused RoPE + fp16 hi/lo q,k --------------
__global__ __launch_bounds__(256) void qkv_gemm_mfma(
    const unsigned short* __restrict__ xh, const unsigned short* __restrict__ xl,
    const unsigned short* __restrict__ wh, const unsigned short* __restrict__ wl,
    const float* __restrict__ cs, const float* __restrict__ sn,
    unsigned short* __restrict__ qh, unsigned short* __restrict__ ql,
    unsigned short* __restrict__ kh, unsigned short* __restrict__ kl,
    float* __restrict__ vout) {
  __shared__ unsigned short AS[8192];
  __shared__ unsigned short BS[8192];
  const int tid = threadIdx.x;
  const int w = tid >> 6, l = tid & 63;
  const int lg = l >> 4, lc = l & 15;
  const int wr = w >> 1, wc = w & 1;
  const int nwg = gridDim.x * gridDim.y;   // 1536, divisible by 8
  int bid = blockIdx.y * gridDim.x + blockIdx.x;
  bid = (bid & 7) * (nwg >> 3) + (bid >> 3);
  const int m0 = (bid / gridDim.x) * 128;
  const int f0 = (bid % gridDim.x) * 128;
  f32x4 acc[4][4] = {};
  gemm_core(xh, xl, wh, wl, AS, BS, m0, f0, acc);
  const int qsel = f0 >> 10;
  const int head = ((f0 & 1023) >> 6) + wc;
  if (qsel == 2) {
#pragma unroll
    for (int mi = 0; mi < 4; ++mi)
#pragma unroll
      for (int nj = 0; nj < 4; ++nj)
#pragma unroll
        for (int r = 0; r < 4; ++r) {
          const int m = m0 + wr*64 + mi*16 + lg*4 + r;
          const int b = m >> 10, n = m & 1023;
          vout[((size_t)(b*HEADS_ + head)*N_ + n)*HD_ + nj*16 + lc] = acc[mi][nj][r];
        }
    return;
  }
  float* tbl = (float*)AS;
  tbl[tid] = cs[tid];
  tbl[256 + tid] = sn[tid];
  __syncthreads();
  // q pre-scaled by (1/8)*log2(e) so attention works in exp2 domain
  const float scale = (qsel == 0) ? 0.18033688011112042f : 1.0f;
  unsigned short* oh = qsel ? kh : qh;
  unsigned short* ol = qsel ? kl : ql;
#pragma unroll
  for (int mi = 0; mi < 4; ++mi)
#pragma unroll
    for (int nj = 0; nj < 4; ++nj) {
      const int d = nj*16 + lc;
#pragma unroll
      for (int r = 0; r < 4; ++r) {
        const int m = m0 + wr*64 + mi*16 + lg*4 + r;
        const int b = m >> 10, n = m & 1023;
        float val = acc[mi][nj][r] * scale;
        float part = __shfl_xor(val, 1);
        if (nj < 2) {   // d < 32 -> rotated
          const int p = d >> 1;
          const int pos = (p < 8) ? (n >> 5) : (n & 31);
          const float c = tbl[pos*8 + (p & 7)];
          const float s = tbl[256 + pos*8 + (p & 7)];
          val = (d & 1) ? (val*c + part*s) : (val*c - part*s);
        }
        const unsigned short hb = f2h(val);
        const size_t off = ((size_t)(b*HEADS_ + head)*N_ + n)*HD_ + d;
        oh[off] = hb;
        ol[off] = f2h(val - h2fl(hb));
      }
    }
}

// ---------------- Proj GEMM (MFMA): out = att·Wproj^T + bias -----------------
__global__ __launch_bounds__(256) void proj_gemm_mfma(
    const unsigned short* __restrict__ ah, const unsigned short* __restrict__ al,
    const unsigned short* __restrict__ wh, const unsigned short* __restrict__ wl,
    const float* __restrict__ bias, float* __restrict__ out) {
  __shared__ unsigned short AS[8192];
  __shared__ unsigned short BS[8192];
  const int tid = threadIdx.x;
  const int w = tid >> 6, l = tid & 63;
  const int lg = l >> 4, lc = l & 15;
  const int wr = w >> 1, wc = w & 1;
  const int nwg = gridDim.x * gridDim.y;   // 512
  int bid = blockIdx.y * gridDim.x + blockIdx.x;
  bid = (bid & 7) * (nwg >> 3) + (bid >> 3);
  const int m0 = (bid / gridDim.x) * 128;
  const int o0 = (bid % gridDim.x) * 128;
  f32x4 acc[4][4] = {};
  gemm_core(ah, al, wh, wl, AS, BS, m0, o0, acc);
#pragma unroll
  for (int nj = 0; nj < 4; ++nj) {
    const int o = o0 + wc*64 + nj*16 + lc;
    const float bv = bias[o];
#pragma unroll
    for (int mi = 0; mi < 4; ++mi)
#pragma unroll
      for (int r = 0; r < 4; ++r) {
        const int m = m0 + wr*64 + mi*16 + lg*4 + r;
        out[(size_t)m*DIM_ + o] = acc[mi][nj][r] + bv;
      }
  }
}

// ---------------- V transpose + fp16 hi/lo split: (bh,n,d) -> (bh,d,n) -------
__global__ __launch_bounds__(256) void vt_split_k(const float* __restrict__ v,
                                                  unsigned short* __restrict__ vth,
                                                  unsigned short* __restrict__ vtl) {
  __shared__ float T[64][65];
  const int tid = threadIdx.x;
  const int nt = blockIdx.x, bh = blockIdx.y;
  {
    const int nr = tid >> 2, dc = (tid & 3) * 16;
    const float* src = v + ((size_t)(bh*N_ + nt*64 + nr))*HD_ + dc;
#pragma unroll
    for (int i = 0; i < 4; ++i) {
      float4 t4 = *(const float4*)(src + i*4);
      T[nr][dc + i*4 + 0] = t4.x;
      T[nr][dc + i*4 + 1] = t4.y;
      T[nr][dc + i*4 + 2] = t4.z;
      T[nr][dc + i*4 + 3] = t4.w;
    }
  }
  __syncthreads();
  const int d = tid >> 2, nb = (tid & 3) * 16;
  __align__(16) unsigned short hh[16];
  __align__(16) unsigned short ll[16];
#pragma unroll
  for (int j = 0; j < 16; ++j) {
    float x = T[nb + j][d];
    unsigned short hb = f2h(x);
    hh[j] = hb;
    ll[j] = f2h(x - h2fl(hb));
  }
  size_t off = ((size_t)(bh*HD_ + d))*N_ + nt*64 + nb;
  *(uint4*)(vth + off)     = *(const uint4*)&hh[0];
  *(uint4*)(vth + off + 8) = *(const uint4*)&hh[8];
  *(uint4*)(vtl + off)     = *(const uint4*)&ll[0];
  *(uint4*)(vtl + off + 8) = *(const uint4*)&ll[8];
}

// ---------------- Flash attention: swapped QK^T, fp16, QBLK=128 --------------
// Block = (bh, qt): 128 q-rows, 4 waves x 32 rows (2 row-tiles of 16).
// S^T = mfma(K, Q): lane holds q-row = lc, keys kt*16 + lg*4 + r.
// P packed fp16 via per-wave swizzled LDS; PV = P*(Vh + Vl) 2-pass.
__global__ __launch_bounds__(256, 3) void attn_mfma_k(
    const unsigned short* __restrict__ qh, const unsigned short* __restrict__ ql,
    const unsigned short* __restrict__ kh, const unsigned short* __restrict__ kl,
    const unsigned short* __restrict__ vth, const unsigned short* __restrict__ vtl,
    unsigned short* __restrict__ aoh, unsigned short* __restrict__ aol) {
  __shared__ unsigned short KhS[4096], KlS[4096], VhS[4096], VlS[4096];
  __shared__ unsigned int Pws[4][512];    // per-wave packed-fp16 P buffer
  const int tid = threadIdx.x;
  const int w = tid >> 6, l = tid & 63;
  const int lg = l >> 4, lc = l & 15;
  const int bh = blockIdx.x, qt = blockIdx.y;   // bh on x: same-bh -> same XCD
  const size_t gb = (size_t)bh * (N_*HD_);

  v8h qfh[2][2], qfl[2][2];
#pragma unroll
  for (int rt = 0; rt < 2; ++rt)
#pragma unroll
    for (int c = 0; c < 2; ++c) {
      const size_t off = gb + (size_t)(qt*128 + w*32 + rt*16 + lc)*HD_ + c*32 + lg*8;
      qfh[rt][c] = *(const v8h*)(qh + off);
      qfl[rt][c] = *(const v8h*)(ql + off);
    }
  f32x4 O[2][4];
#pragma unroll
  for (int rt = 0; rt < 2; ++rt)
#pragma unroll
    for (int dt = 0; dt < 4; ++dt) O[rt][dt] = (f32x4){0.f, 0.f, 0.f, 0.f};
  float mrow[2] = {-INFINITY, -INFINITY};
  float lrow[2] = {0.f, 0.f};

  const int sr8 = l >> 3;           // staging row within 8
  const int sch = (l & 7) ^ sr8;    // pre-swizzled source chunk
  char* PB = (char*)&Pws[w][0];
  const int psw = (lc & 7) << 4;

  for (int t = 0; t < 16; ++t) {
    // ---- stage K (keys x d) and V^T (d x keys) tiles, fp16 hi/lo, swizzled
#pragma unroll
    for (int i = 0; i < 2; ++i) {
      const int row = w*16 + i*8 + sr8;
      const int lbase = (w*16 + i*8)*64;             // wave-uniform LDS base
      const size_t kge = gb + (size_t)(t*64 + row)*HD_ + sch*8;
      const size_t vge = gb + (size_t)row*N_ + t*64 + sch*8;
      gload16(KhS + lbase, kh + kge);
      gload16(KlS + lbase, kl + kge);
      gload16(VhS + lbase, vth + vge);
      gload16(VlS + lbase, vtl + vge);
    }
    __syncthreads();
    // ---- QK^T swapped: S^T[key][q], 3-pass fp16
    f32x4 s[2][4];
#pragma unroll
    for (int rt = 0; rt < 2; ++rt)
#pragma unroll
      for (int kt = 0; kt < 4; ++kt) s[rt][kt] = (f32x4){0.f, 0.f, 0.f, 0.f};
#pragma unroll
    for (int kt = 0; kt < 4; ++kt) {
      const int row = kt*16 + lc;
      const int sw = (row & 7) << 4;
#pragma unroll
      for (int c = 0; c < 2; ++c) {
        const int boff = row*128 + ((c*64 + lg*16) ^ sw);
        v8h kfh = *(const v8h*)((const char*)KhS + boff);
        v8h kfl = *(const v8h*)((const char*)KlS + boff);
#pragma unroll
        for (int rt = 0; rt < 2; ++rt) {
          s[rt][kt] = __builtin_amdgcn_mfma_f32_16x16x32_f16(kfh, qfh[rt][c], s[rt][kt], 0, 0, 0);
          s[rt][kt] = __builtin_amdgcn_mfma_f32_16x16x32_f16(kfh, qfl[rt][c], s[rt][kt], 0, 0, 0);
          s[rt][kt] = __builtin_amdgcn_mfma_f32_16x16x32_f16(kfl, qfh[rt][c], s[rt][kt], 0, 0, 0);
        }
      }
    }
    // ---- tile max (per-lane row lc; reduce across lg groups)
    float tm[2];
#pragma unroll
    for (int rt = 0; rt < 2; ++rt) {
      float m0 = fmaxf(fmaxf(s[rt][0][0], s[rt][0][1]), fmaxf(s[rt][0][2], s[rt][0][3]));
#pragma unroll
      for (int kt = 1; kt < 4; ++kt) {
        m0 = fmaxf(m0, fmaxf(fmaxf(s[rt][kt][0], s[rt][kt][1]),
                             fmaxf(s[rt][kt][2], s[rt][kt][3])));
      }
      m0 = fmaxf(m0, __shfl_xor(m0, 16));
      m0 = fmaxf(m0, __shfl_xor(m0, 32));
      tm[rt] = m0;
    }
    // ---- defer-max: rescale only if some row grew by > 8 (exp2 domain)
    const bool ok = (tm[0] <= mrow[0] + 8.f) && (tm[1] <= mrow[1] + 8.f);
    if (!__all(ok)) {
      float corr[2];
#pragma unroll
      for (int rt = 0; rt < 2; ++rt) {
        const float mn = fmaxf(mrow[rt], tm[rt]);
        corr[rt] = fexp2(mrow[rt] - mn);
        mrow[rt] = mn;
        lrow[rt] *= corr[rt];
      }
#pragma unroll
      for (int rt = 0; rt < 2; ++rt)
#pragma unroll
        for (int r = 0; r < 4; ++r) {
          const float cr = __shfl(corr[rt], lg*4 + r);
#pragma unroll
          for (int dt = 0; dt < 4; ++dt) O[rt][dt][r] *= cr;
        }
    }
    // ---- P = exp2(s - m); psum; pack fp16 -> per-wave LDS; read A-frags
    u32x4 pa[2][2];
#pragma unroll
    for (int rt = 0; rt < 2; ++rt) {
      float ps = 0.f;
      float p[4][4];
#pragma unroll
      for (int kt = 0; kt < 4; ++kt)
#pragma unroll
        for (int r = 0; r < 4; ++r) {
          const float pv = fexp2(s[rt][kt][r] - mrow[rt]);
          p[kt][r] = pv;
          ps += pv;
        }
      ps += __shfl_xor(ps, 16);
      ps += __shfl_xor(ps, 32);
      lrow[rt] += ps;
#pragma unroll
      for (int kt = 0; kt < 4; ++kt) {
        uint2 pw;
        pw.x = pkh2(p[kt][0], p[kt][1]);
        pw.y = pkh2(p[kt][2], p[kt][3]);
        *(uint2*)(PB + lc*128 + ((kt*32 + lg*8) ^ psw)) = pw;
      }
#pragma unroll
      for (int c = 0; c < 2; ++c)
        pa[rt][c] = *(const u32x4*)(PB + lc*128 + ((c*64 + lg*16) ^ psw));
    }
    // ---- PV: O += P * (Vh + Vl), 2-pass
#pragma unroll
    for (int dt = 0; dt < 4; ++dt) {
      const int row = dt*16 + lc;
      const int sw = (row & 7) << 4;
#pragma unroll
      for (int c = 0; c < 2; ++c) {
        const int boff = row*128 + ((c*64 + lg*16) ^ sw);
        v8h vfh = *(const v8h*)((const char*)VhS + boff);
        v8h vfl = *(const v8h*)((const char*)VlS + boff);
#pragma unroll
        for (int rt = 0; rt < 2; ++rt) {
          const v8h pv = __builtin_bit_cast(v8h, pa[rt][c]);
          O[rt][dt] = __builtin_amdgcn_mfma_f32_16x16x32_f16(pv, vfh, O[rt][dt], 0, 0, 0);
          O[rt][dt] = __builtin_amdgcn_mfma_f32_16x16x32_f16(pv, vfl, O[rt][dt], 0, 0, 0);
        }
      }
    }
    __syncthreads();
  }
  // ---- epilogue: attout bf16 hi/lo (proj input), (B, N, DIM)
  const int b = bh >> 4, h = bh & 15;
#pragma unroll
  for (int rt = 0; rt < 2; ++rt) {
    const float myinv = 1.0f / lrow[rt];
#pragma unroll
    for (int r = 0; r < 4; ++r) {
      const float iv = __shfl(myinv, lg*4 + r);
      const int n = qt*128 + w*32 + rt*16 + lg*4 + r;
      const size_t base = ((size_t)(b*N_ + n))*DIM_ + h*HD_ + lc;
#pragma unroll
      for (int dt = 0; dt < 4; ++dt) {
        const float val = O[rt][dt][r] * iv;
        const unsigned short hb = f2bf(val);
        aoh[base + dt*16] = hb;
        aol[base + dt*16] = f2bf(val - bf2f(hb));
      }
    }
  }
}

extern "C" void kernel_launch(void* const* d_in, const int* in_sizes, int n_in,
                              void* d_out, int out_size, void* d_ws, size_t ws_size,
                              hipStream_t stream) {
  const float* x     = (const float*)d_in[0];
  const float* Wqkv  = (const float*)d_in[1];
  const float* Wproj = (const float*)d_in[2];
  const float* bproj = (const float*)d_in[3];
  float* out = (float*)d_out;

  unsigned short* xh  = (unsigned short*)d_ws;             // 8388608
  unsigned short* xl  = xh  + 8388608;                     // 8388608
  unsigned short* wqh = xl  + 8388608;                     // 3145728
  unsigned short* wql = wqh + 3145728;
  unsigned short* wph = wql + 3145728;                     // 1048576
  unsigned short* wpl = wph + 1048576;
  unsigned short* qh  = wpl + 1048576;                     // 8388608 x4
  unsigned short* ql  = qh  + 8388608;
  unsigned short* kh  = ql  + 8388608;
  unsigned short* kl  = kh  + 8388608;
  float* v  = (float*)(kl + 8388608);                      // 8388608 f32
  float* cs = v + 8388608;                                 // 256
  float* sn = cs + 256;                                    // 256
  // aliases (lifetimes disjoint)
  unsigned short* vth = xh;
  unsigned short* vtl = xl;
  unsigned short* aoh = (unsigned short*)v;
  unsigned short* aol = aoh + 8388608;

  hipLaunchKernelGGL(rope_table_k, dim3(1), dim3(256), 0, stream, cs, sn);
  hipLaunchKernelGGL(split_k, dim3(8192), dim3(256), 0, stream, x,     xh,  xl,  2097152);
  hipLaunchKernelGGL(split_k, dim3(3072), dim3(256), 0, stream, Wqkv,  wqh, wql, 786432);
  hipLaunchKernelGGL(split_k, dim3(1024), dim3(256), 0, stream, Wproj, wph, wpl, 262144);
  hipLaunchKernelGGL(qkv_gemm_mfma, dim3(24, 64), dim3(256), 0, stream,
                     xh, xl, wqh, wql, cs, sn, qh, ql, kh, kl, v);
  hipLaunchKernelGGL(vt_split_k, dim3(16, 128), dim3(256), 0, stream, v, vth, vtl);
  hipLaunchKernelGGL(attn_mfma_k, dim3(128, 8), dim3(256), 0, stream,
                     qh, ql, kh, kl, vth, vtl, aoh, aol);
  hipLaunchKernelGGL(proj_gemm_mfma, dim3(8, 64), dim3(256), 0, stream,
                     aoh, aol, wph, wpl, bproj, out);
}

// Round 6
// 268.585 us; speedup vs baseline: 7.9136x; 1.2636x over previous
//
#include <hip/hip_runtime.h>
#include <math.h>

#define DIM_ 1024
#define HEADS_ 16
#define HD_ 64
#define B_ 8
#define N_ 1024
#define M_TOT 8192
#define QKV_SZ (B_*HEADS_*N_*HD_)   // 8388608 elements per (b,h,n,d) array

typedef __attribute__((ext_vector_type(4))) float f32x4;  // MFMA C/D
typedef _Float16 v8h __attribute__((ext_vector_type(8))); // 8 fp16
typedef __attribute__((ext_vector_type(4))) unsigned int u32x4;

static __device__ __forceinline__ unsigned short f2bf(float x) {
  unsigned u = __float_as_uint(x);
  u += 0x7FFFu + ((u >> 16) & 1u);
  return (unsigned short)(u >> 16);
}
static __device__ __forceinline__ float bf2f(unsigned short h) {
  return __uint_as_float(((unsigned)h) << 16);
}
static __device__ __forceinline__ unsigned short f2h(float x) {
  _Float16 h = (_Float16)x;
  return __builtin_bit_cast(unsigned short, h);
}
static __device__ __forceinline__ float h2fl(unsigned short u) {
  return (float)__builtin_bit_cast(_Float16, u);
}
static __device__ __forceinline__ float fexp2(float x) {
  return __builtin_amdgcn_exp2f(x);
}
static __device__ __forceinline__ unsigned pkh2(float a, float b) {
  auto t = __builtin_amdgcn_cvt_pkrtz(a, b);   // __fp16 ext_vector(2), 4 bytes
  return __builtin_bit_cast(unsigned, t);
}

static __device__ __forceinline__ void gload16(unsigned short* lds_base,
                                               const unsigned short* g) {
  __builtin_amdgcn_global_load_lds(
      (const __attribute__((address_space(1))) unsigned int*)g,
      (__attribute__((address_space(3))) unsigned int*)lds_base, 16, 0, 0);
}

// ---------------- fp32 -> fp16 hi/lo split -----------------------------------
__global__ __launch_bounds__(256) void split2h_k(const float* __restrict__ src,
                                                 unsigned short* __restrict__ hi,
                                                 unsigned short* __restrict__ lo,
                                                 int n4) {
  int i = blockIdx.x * 256 + threadIdx.x;
  if (i >= n4) return;
  float4 x = ((const float4*)src)[i];
  ushort4 h, l;
  h.x = f2h(x.x); l.x = f2h(x.x - h2fl(h.x));
  h.y = f2h(x.y); l.y = f2h(x.y - h2fl(h.y));
  h.z = f2h(x.z); l.z = f2h(x.z - h2fl(h.z));
  h.w = f2h(x.w); l.w = f2h(x.w - h2fl(h.w));
  ((ushort4*)hi)[i] = h;
  ((ushort4*)lo)[i] = l;
}

// ---------------- fp32 -> fp16 hi only ---------------------------------------
__global__ __launch_bounds__(256) void split1h_k(const float* __restrict__ src,
                                                 unsigned short* __restrict__ hi,
                                                 int n4) {
  int i = blockIdx.x * 256 + threadIdx.x;
  if (i >= n4) return;
  float4 x = ((const float4*)src)[i];
  ushort4 h;
  h.x = f2h(x.x); h.y = f2h(x.y); h.z = f2h(x.z); h.w = f2h(x.w);
  ((ushort4*)hi)[i] = h;
}

// ---------------- RoPE table (fp64; angles reach ~1608 rad) ------------------
__global__ void rope_table_k(float* cs, float* sn) {
  int i = threadIdx.x;
  if (i < 256) {
    int pos = i >> 3, j = i & 7;
    double u = -1.0 + (double)pos * (2.0/31.0);
    double ang = u * ((1.0 + 73.0*(double)j) * 3.14159265358979323846);
    cs[i] = (float)cos(ang);
    sn[i] = (float)sin(ang);
  }
}

// ---------------- 2-pass fp16 MFMA GEMM core ---------------------------------
// C[m,f] = A[m,:]·B[f,:]. DUAL_A=1: A = hi+lo, B = hi. DUAL_A=0: A = hi, B = hi+lo.
// 128x128 tile, BK=64, 4 waves 2x2, per-wave 4x4 16x16 fragments.
// LDS tile row = 128B (64 fp16 = one BK slice); 16B chunks XOR-swizzled by
// (row&7); swizzle applied on the GLOBAL source (linear global_load_lds dest).
template<int DUAL_A>
static __device__ __forceinline__ void gemm_core2(
    const unsigned short* __restrict__ ah, const unsigned short* __restrict__ al,
    const unsigned short* __restrict__ bh, const unsigned short* __restrict__ bl,
    unsigned short* S0, unsigned short* S1, unsigned short* S2,
    int m0, int f0, f32x4 acc[4][4]) {
  const int tid = threadIdx.x;
  const int w = tid >> 6, l = tid & 63;
  const int lg = l >> 4, lc = l & 15;
  const int wr = w >> 1, wc = w & 1;
  const int r8 = l >> 3;               // staging row within 8
  const int ch = (l & 7) ^ r8;         // pre-swizzled source chunk
  const int kc = ch * 8;               // element offset of chunk
  for (int k0 = 0; k0 < 1024; k0 += 64) {
#pragma unroll
    for (int r = 0; r < 4; ++r) {
      const int row = r*32 + w*8 + r8;
      const size_t ao = (size_t)(m0 + row)*1024 + k0 + kc;
      const size_t bo = (size_t)(f0 + row)*1024 + k0 + kc;
      const int d = r*2048 + w*512;    // shorts (lane*16B added by HW)
      gload16(S0 + d, ah + ao);
      gload16(S2 + d, bh + bo);
      if (DUAL_A) gload16(S1 + d, al + ao);
      else        gload16(S1 + d, bl + bo);
    }
    __syncthreads();
#pragma unroll
    for (int c = 0; c < 2; ++c) {
      v8h a0[4], a1[4], b0[4], b1[4];
#pragma unroll
      for (int mi = 0; mi < 4; ++mi) {
        const int row = wr*64 + mi*16 + lc;
        const int bo = row*128 + ((c*64 + lg*16) ^ ((row & 7) << 4));
        a0[mi] = *(const v8h*)((const char*)S0 + bo);
        if (DUAL_A) a1[mi] = *(const v8h*)((const char*)S1 + bo);
      }
#pragma unroll
      for (int nj = 0; nj < 4; ++nj) {
        const int row = wc*64 + nj*16 + lc;
        const int bo = row*128 + ((c*64 + lg*16) ^ ((row & 7) << 4));
        b0[nj] = *(const v8h*)((const char*)S2 + bo);
        if (!DUAL_A) b1[nj] = *(const v8h*)((const char*)S1 + bo);
      }
#pragma unroll
      for (int mi = 0; mi < 4; ++mi)
#pragma unroll
        for (int nj = 0; nj < 4; ++nj) {
          acc[mi][nj] = __builtin_amdgcn_mfma_f32_16x16x32_f16(a0[mi], b0[nj], acc[mi][nj], 0, 0, 0);
          if (DUAL_A)
            acc[mi][nj] = __builtin_amdgcn_mfma_f32_16x16x32_f16(a1[mi], b0[nj], acc[mi][nj], 0, 0, 0);
          else
            acc[mi][nj] = __builtin_amdgcn_mfma_f32_16x16x32_f16(a0[mi], b1[nj], acc[mi][nj], 0, 0, 0);
        }
    }
    __syncthreads();
  }
}

// ---------------- QKV GEMM (MFMA) + fused RoPE + fp16 hi/lo q,k --------------
__global__ __launch_bounds__(256) void qkv_gemm_mfma(
    const unsigned short* __restrict__ xh, const unsigned short* __restrict__ xl,
    const unsigned short* __restrict__ wh,
    const float* __restrict__ cs, const float* __restrict__ sn,
    unsigned short* __restrict__ qh, unsigned short* __restrict__ ql,
    unsigned short* __restrict__ kh, unsigned short* __restrict__ kl,
    float* __restrict__ vout) {
  __shared__ unsigned short S0[8192], S1[8192], S2[8192];   // 48 KB
  const int tid = threadIdx.x;
  const int w = tid >> 6, l = tid & 63;
  const int lg = l >> 4, lc = l & 15;
  const int wr = w >> 1, wc = w & 1;
  const int nwg = gridDim.x * gridDim.y;   // 1536, divisible by 8
  int bid = blockIdx.y * gridDim.x + blockIdx.x;
  bid = (bid & 7) * (nwg >> 3) + (bid >> 3);
  const int m0 = (bid / gridDim.x) * 128;
  const int f0 = (bid % gridDim.x) * 128;
  f32x4 acc[4][4] = {};
  gemm_core2<1>(xh, xl, wh, wh, S0, S1, S2, m0, f0, acc);
  const int qsel = f0 >> 10;
  const int head = ((f0 & 1023) >> 6) + wc;
  if (qsel == 2) {
#pragma unroll
    for (int mi = 0; mi < 4; ++mi)
#pragma unroll
      for (int nj = 0; nj < 4; ++nj)
#pragma unroll
        for (int r = 0; r < 4; ++r) {
          const int m = m0 + wr*64 + mi*16 + lg*4 + r;
          const int b = m >> 10, n = m & 1023;
          vout[((size_t)(b*HEADS_ + head)*N_ + n)*HD_ + nj*16 + lc] = acc[mi][nj][r];
        }
    return;
  }
  float* tbl = (float*)S0;
  tbl[tid] = cs[tid];
  tbl[256 + tid] = sn[tid];
  __syncthreads();
  // q pre-scaled by (1/8)*log2(e) so attention works in exp2 domain
  const float scale = (qsel == 0) ? 0.18033688011112042f : 1.0f;
  unsigned short* oh = qsel ? kh : qh;
  unsigned short* ol = qsel ? kl : ql;
#pragma unroll
  for (int mi = 0; mi < 4; ++mi)
#pragma unroll
    for (int nj = 0; nj < 4; ++nj) {
      const int d = nj*16 + lc;
#pragma unroll
      for (int r = 0; r < 4; ++r) {
        const int m = m0 + wr*64 + mi*16 + lg*4 + r;
        const int b = m >> 10, n = m & 1023;
        float val = acc[mi][nj][r] * scale;
        float part = __shfl_xor(val, 1);
        if (nj < 2) {   // d < 32 -> rotated
          const int p = d >> 1;
          const int pos = (p < 8) ? (n >> 5) : (n & 31);
          const float c = tbl[pos*8 + (p & 7)];
          const float s = tbl[256 + pos*8 + (p & 7)];
          val = (d & 1) ? (val*c + part*s) : (val*c - part*s);
        }
        const unsigned short hb = f2h(val);
        const size_t off = ((size_t)(b*HEADS_ + head)*N_ + n)*HD_ + d;
        oh[off] = hb;
        ol[off] = f2h(val - h2fl(hb));
      }
    }
}

// ---------------- Proj GEMM (MFMA): out = att·(Wh+Wl)^T + bias ---------------
__global__ __launch_bounds__(256) void proj_gemm_mfma(
    const unsigned short* __restrict__ ah,
    const unsigned short* __restrict__ wh, const unsigned short* __restrict__ wl,
    const float* __restrict__ bias, float* __restrict__ out) {
  __shared__ unsigned short S0[8192], S1[8192], S2[8192];
  const int tid = threadIdx.x;
  const int w = tid >> 6, l = tid & 63;
  const int lg = l >> 4, lc = l & 15;
  const int wr = w >> 1, wc = w & 1;
  const int nwg = gridDim.x * gridDim.y;   // 512
  int bid = blockIdx.y * gridDim.x + blockIdx.x;
  bid = (bid & 7) * (nwg >> 3) + (bid >> 3);
  const int m0 = (bid / gridDim.x) * 128;
  const int o0 = (bid % gridDim.x) * 128;
  f32x4 acc[4][4] = {};
  gemm_core2<0>(ah, ah, wh, wl, S0, S1, S2, m0, o0, acc);
#pragma unroll
  for (int nj = 0; nj < 4; ++nj) {
    const int o = o0 + wc*64 + nj*16 + lc;
    const float bv = bias[o];
#pragma unroll
    for (int mi = 0; mi < 4; ++mi)
#pragma unroll
      for (int r = 0; r < 4; ++r) {
        const int m = m0 + wr*64 + mi*16 + lg*4 + r;
        out[(size_t)m*DIM_ + o] = acc[mi][nj][r] + bv;
      }
  }
}

// ---------------- V transpose + fp16 hi/lo split: (bh,n,d) -> (bh,d,n) -------
__global__ __launch_bounds__(256) void vt_split_k(const float* __restrict__ v,
                                                  unsigned short* __restrict__ vth,
                                                  unsigned short* __restrict__ vtl) {
  __shared__ float T[64][65];
  const int tid = threadIdx.x;
  const int nt = blockIdx.x, bh = blockIdx.y;
  {
    const int nr = tid >> 2, dc = (tid & 3) * 16;
    const float* src = v + ((size_t)(bh*N_ + nt*64 + nr))*HD_ + dc;
#pragma unroll
    for (int i = 0; i < 4; ++i) {
      float4 t4 = *(const float4*)(src + i*4);
      T[nr][dc + i*4 + 0] = t4.x;
      T[nr][dc + i*4 + 1] = t4.y;
      T[nr][dc + i*4 + 2] = t4.z;
      T[nr][dc + i*4 + 3] = t4.w;
    }
  }
  __syncthreads();
  const int d = tid >> 2, nb = (tid & 3) * 16;
  __align__(16) unsigned short hh[16];
  __align__(16) unsigned short ll[16];
#pragma unroll
  for (int j = 0; j < 16; ++j) {
    float x = T[nb + j][d];
    unsigned short hb = f2h(x);
    hh[j] = hb;
    ll[j] = f2h(x - h2fl(hb));
  }
  size_t off = ((size_t)(bh*HD_ + d))*N_ + nt*64 + nb;
  *(uint4*)(vth + off)     = *(const uint4*)&hh[0];
  *(uint4*)(vth + off + 8) = *(const uint4*)&hh[8];
  *(uint4*)(vtl + off)     = *(const uint4*)&ll[0];
  *(uint4*)(vtl + off + 8) = *(const uint4*)&ll[8];
}

// ---------------- Flash attention: swapped QK^T, fp16, QBLK=128 --------------
__global__ __launch_bounds__(256, 3) void attn_mfma_k(
    const unsigned short* __restrict__ qh, const unsigned short* __restrict__ ql,
    const unsigned short* __restrict__ kh, const unsigned short* __restrict__ kl,
    const unsigned short* __restrict__ vth, const unsigned short* __restrict__ vtl,
    unsigned short* __restrict__ aoh) {
  __shared__ unsigned short KhS[4096], KlS[4096], VhS[4096], VlS[4096];
  __shared__ unsigned int Pws[4][512];
  const int tid = threadIdx.x;
  const int w = tid >> 6, l = tid & 63;
  const int lg = l >> 4, lc = l & 15;
  const int bh = blockIdx.x, qt = blockIdx.y;
  const size_t gb = (size_t)bh * (N_*HD_);

  v8h qfh[2][2], qfl[2][2];
#pragma unroll
  for (int rt = 0; rt < 2; ++rt)
#pragma unroll
    for (int c = 0; c < 2; ++c) {
      const size_t off = gb + (size_t)(qt*128 + w*32 + rt*16 + lc)*HD_ + c*32 + lg*8;
      qfh[rt][c] = *(const v8h*)(qh + off);
      qfl[rt][c] = *(const v8h*)(ql + off);
    }
  f32x4 O[2][4];
#pragma unroll
  for (int rt = 0; rt < 2; ++rt)
#pragma unroll
    for (int dt = 0; dt < 4; ++dt) O[rt][dt] = (f32x4){0.f, 0.f, 0.f, 0.f};
  float mrow[2] = {-INFINITY, -INFINITY};
  float lrow[2] = {0.f, 0.f};

  const int sr8 = l >> 3;
  const int sch = (l & 7) ^ sr8;
  char* PB = (char*)&Pws[w][0];
  const int psw = (lc & 7) << 4;

  for (int t = 0; t < 16; ++t) {
#pragma unroll
    for (int i = 0; i < 2; ++i) {
      const int row = w*16 + i*8 + sr8;
      const int lbase = (w*16 + i*8)*64;
      const size_t kge = gb + (size_t)(t*64 + row)*HD_ + sch*8;
      const size_t vge = gb + (size_t)row*N_ + t*64 + sch*8;
      gload16(KhS + lbase, kh + kge);
      gload16(KlS + lbase, kl + kge);
      gload16(VhS + lbase, vth + vge);
      gload16(VlS + lbase, vtl + vge);
    }
    __syncthreads();
    f32x4 s[2][4];
#pragma unroll
    for (int rt = 0; rt < 2; ++rt)
#pragma unroll
      for (int kt = 0; kt < 4; ++kt) s[rt][kt] = (f32x4){0.f, 0.f, 0.f, 0.f};
#pragma unroll
    for (int kt = 0; kt < 4; ++kt) {
      const int row = kt*16 + lc;
      const int sw = (row & 7) << 4;
#pragma unroll
      for (int c = 0; c < 2; ++c) {
        const int boff = row*128 + ((c*64 + lg*16) ^ sw);
        v8h kfh = *(const v8h*)((const char*)KhS + boff);
        v8h kfl = *(const v8h*)((const char*)KlS + boff);
#pragma unroll
        for (int rt = 0; rt < 2; ++rt) {
          s[rt][kt] = __builtin_amdgcn_mfma_f32_16x16x32_f16(kfh, qfh[rt][c], s[rt][kt], 0, 0, 0);
          s[rt][kt] = __builtin_amdgcn_mfma_f32_16x16x32_f16(kfh, qfl[rt][c], s[rt][kt], 0, 0, 0);
          s[rt][kt] = __builtin_amdgcn_mfma_f32_16x16x32_f16(kfl, qfh[rt][c], s[rt][kt], 0, 0, 0);
        }
      }
    }
    float tm[2];
#pragma unroll
    for (int rt = 0; rt < 2; ++rt) {
      float m0 = fmaxf(fmaxf(s[rt][0][0], s[rt][0][1]), fmaxf(s[rt][0][2], s[rt][0][3]));
#pragma unroll
      for (int kt = 1; kt < 4; ++kt) {
        m0 = fmaxf(m0, fmaxf(fmaxf(s[rt][kt][0], s[rt][kt][1]),
                             fmaxf(s[rt][kt][2], s[rt][kt][3])));
      }
      m0 = fmaxf(m0, __shfl_xor(m0, 16));
      m0 = fmaxf(m0, __shfl_xor(m0, 32));
      tm[rt] = m0;
    }
    const bool ok = (tm[0] <= mrow[0] + 8.f) && (tm[1] <= mrow[1] + 8.f);
    if (!__all(ok)) {
      float corr[2];
#pragma unroll
      for (int rt = 0; rt < 2; ++rt) {
        const float mn = fmaxf(mrow[rt], tm[rt]);
        corr[rt] = fexp2(mrow[rt] - mn);
        mrow[rt] = mn;
        lrow[rt] *= corr[rt];
      }
#pragma unroll
      for (int rt = 0; rt < 2; ++rt)
#pragma unroll
        for (int r = 0; r < 4; ++r) {
          const float cr = __shfl(corr[rt], lg*4 + r);
#pragma unroll
          for (int dt = 0; dt < 4; ++dt) O[rt][dt][r] *= cr;
        }
    }
    u32x4 pa[2][2];
#pragma unroll
    for (int rt = 0; rt < 2; ++rt) {
      float ps = 0.f;
      float p[4][4];
#pragma unroll
      for (int kt = 0; kt < 4; ++kt)
#pragma unroll
        for (int r = 0; r < 4; ++r) {
          const float pv = fexp2(s[rt][kt][r] - mrow[rt]);
          p[kt][r] = pv;
          ps += pv;
        }
      ps += __shfl_xor(ps, 16);
      ps += __shfl_xor(ps, 32);
      lrow[rt] += ps;
#pragma unroll
      for (int kt = 0; kt < 4; ++kt) {
        uint2 pw;
        pw.x = pkh2(p[kt][0], p[kt][1]);
        pw.y = pkh2(p[kt][2], p[kt][3]);
        *(uint2*)(PB + lc*128 + ((kt*32 + lg*8) ^ psw)) = pw;
      }
#pragma unroll
      for (int c = 0; c < 2; ++c)
        pa[rt][c] = *(const u32x4*)(PB + lc*128 + ((c*64 + lg*16) ^ psw));
    }
#pragma unroll
    for (int dt = 0; dt < 4; ++dt) {
      const int row = dt*16 + lc;
      const int sw = (row & 7) << 4;
#pragma unroll
      for (int c = 0; c < 2; ++c) {
        const int boff = row*128 + ((c*64 + lg*16) ^ sw);
        v8h vfh = *(const v8h*)((const char*)VhS + boff);
        v8h vfl = *(const v8h*)((const char*)VlS + boff);
#pragma unroll
        for (int rt = 0; rt < 2; ++rt) {
          const v8h pv = __builtin_bit_cast(v8h, pa[rt][c]);
          O[rt][dt] = __builtin_amdgcn_mfma_f32_16x16x32_f16(pv, vfh, O[rt][dt], 0, 0, 0);
          O[rt][dt] = __builtin_amdgcn_mfma_f32_16x16x32_f16(pv, vfl, O[rt][dt], 0, 0, 0);
        }
      }
    }
    __syncthreads();
  }
  // ---- epilogue: attout fp16 hi only (proj A operand), (B, N, DIM)
  const int b = bh >> 4, h = bh & 15;
#pragma unroll
  for (int rt = 0; rt < 2; ++rt) {
    const float myinv = 1.0f / lrow[rt];
#pragma unroll
    for (int r = 0; r < 4; ++r) {
      const float iv = __shfl(myinv, lg*4 + r);
      const int n = qt*128 + w*32 + rt*16 + lg*4 + r;
      const size_t base = ((size_t)(b*N_ + n))*DIM_ + h*HD_ + lc;
#pragma unroll
      for (int dt = 0; dt < 4; ++dt)
        aoh[base + dt*16] = f2h(O[rt][dt][r] * iv);
    }
  }
}

extern "C" void kernel_launch(void* const* d_in, const int* in_sizes, int n_in,
                              void* d_out, int out_size, void* d_ws, size_t ws_size,
                              hipStream_t stream) {
  const float* x     = (const float*)d_in[0];
  const float* Wqkv  = (const float*)d_in[1];
  const float* Wproj = (const float*)d_in[2];
  const float* bproj = (const float*)d_in[3];
  float* out = (float*)d_out;

  unsigned short* xh  = (unsigned short*)d_ws;             // 8388608
  unsigned short* xl  = xh  + 8388608;                     // 8388608
  unsigned short* wqh = xl  + 8388608;                     // 3145728
  unsigned short* wph = wqh + 3145728;                     // 1048576
  unsigned short* wpl = wph + 1048576;                     // 1048576
  unsigned short* qh  = wpl + 1048576;                     // 8388608 x4
  unsigned short* ql  = qh  + 8388608;
  unsigned short* kh  = ql  + 8388608;
  unsigned short* kl  = kh  + 8388608;
  float* v  = (float*)(kl + 8388608);                      // 8388608 f32
  float* cs = v + 8388608;                                 // 256
  float* sn = cs + 256;                                    // 256
  // aliases (lifetimes disjoint)
  unsigned short* vth = xh;                 // after qkv, x-splits are dead
  unsigned short* vtl = xl;
  unsigned short* aoh = (unsigned short*)v; // after vt_split, v is dead

  hipLaunchKernelGGL(rope_table_k, dim3(1), dim3(256), 0, stream, cs, sn);
  hipLaunchKernelGGL(split2h_k, dim3(8192), dim3(256), 0, stream, x,     xh, xl, 2097152);
  hipLaunchKernelGGL(split1h_k, dim3(3072), dim3(256), 0, stream, Wqkv,  wqh, 786432);
  hipLaunchKernelGGL(split2h_k, dim3(1024), dim3(256), 0, stream, Wproj, wph, wpl, 262144);
  hipLaunchKernelGGL(qkv_gemm_mfma, dim3(24, 64), dim3(256), 0, stream,
                     xh, xl, wqh, cs, sn, qh, ql, kh, kl, v);
  hipLaunchKernelGGL(vt_split_k, dim3(16, 128), dim3(256), 0, stream, v, vth, vtl);
  hipLaunchKernelGGL(attn_mfma_k, dim3(128, 8), dim3(256), 0, stream,
                     qh, ql, kh, kl, vth, vtl, aoh);
  hipLaunchKernelGGL(proj_gemm_mfma, dim3(8, 64), dim3(256), 0, stream,
                     aoh, wph, wpl, bproj, out);
}

// Round 7
// 240.619 us; speedup vs baseline: 8.8334x; 1.1162x over previous
//
#include <hip/hip_runtime.h>
#include <math.h>

#define DIM_ 1024
#define HEADS_ 16
#define HD_ 64
#define B_ 8
#define N_ 1024
#define M_TOT 8192

typedef __attribute__((ext_vector_type(4))) float f32x4;  // MFMA C/D
typedef _Float16 v8h __attribute__((ext_vector_type(8))); // 8 fp16
typedef __attribute__((ext_vector_type(4))) unsigned int u32x4;

static __device__ __forceinline__ unsigned short f2h(float x) {
  _Float16 h = (_Float16)x;
  return __builtin_bit_cast(unsigned short, h);
}
static __device__ __forceinline__ float h2fl(unsigned short u) {
  return (float)__builtin_bit_cast(_Float16, u);
}
static __device__ __forceinline__ float fexp2(float x) {
  return __builtin_amdgcn_exp2f(x);
}
static __device__ __forceinline__ unsigned pkh2(float a, float b) {
  auto t = __builtin_amdgcn_cvt_pkrtz(a, b);   // 2 x fp16 packed
  return __builtin_bit_cast(unsigned, t);
}

static __device__ __forceinline__ void gload16(unsigned short* lds_base,
                                               const unsigned short* g) {
  __builtin_amdgcn_global_load_lds(
      (const __attribute__((address_space(1))) unsigned int*)g,
      (__attribute__((address_space(3))) unsigned int*)lds_base, 16, 0, 0);
}

// ---------------- fp32 -> fp16 hi/lo split -----------------------------------
__global__ __launch_bounds__(256) void split2h_k(const float* __restrict__ src,
                                                 unsigned short* __restrict__ hi,
                                                 unsigned short* __restrict__ lo,
                                                 int n4) {
  int i = blockIdx.x * 256 + threadIdx.x;
  if (i >= n4) return;
  float4 x = ((const float4*)src)[i];
  ushort4 h, l;
  h.x = f2h(x.x); l.x = f2h(x.x - h2fl(h.x));
  h.y = f2h(x.y); l.y = f2h(x.y - h2fl(h.y));
  h.z = f2h(x.z); l.z = f2h(x.z - h2fl(h.z));
  h.w = f2h(x.w); l.w = f2h(x.w - h2fl(h.w));
  ((ushort4*)hi)[i] = h;
  ((ushort4*)lo)[i] = l;
}

// ---------------- fp32 -> fp16 hi only ---------------------------------------
__global__ __launch_bounds__(256) void split1h_k(const float* __restrict__ src,
                                                 unsigned short* __restrict__ hi,
                                                 int n4) {
  int i = blockIdx.x * 256 + threadIdx.x;
  if (i >= n4) return;
  float4 x = ((const float4*)src)[i];
  ushort4 h;
  h.x = f2h(x.x); h.y = f2h(x.y); h.z = f2h(x.z); h.w = f2h(x.w);
  ((ushort4*)hi)[i] = h;
}

// ---------------- RoPE table (fp64; angles reach ~1608 rad) ------------------
__global__ void rope_table_k(float* cs, float* sn) {
  int i = threadIdx.x;
  if (i < 256) {
    int pos = i >> 3, j = i & 7;
    double u = -1.0 + (double)pos * (2.0/31.0);
    double ang = u * ((1.0 + 73.0*(double)j) * 3.14159265358979323846);
    cs[i] = (float)cos(ang);
    sn[i] = (float)sin(ang);
  }
}

// ---------------- 2-pass fp16 MFMA GEMM core ---------------------------------
// DUAL_A=1: C = (Ah+Al)·Bh^T. DUAL_A=0: C = Ah·(Bh+Bl)^T.
// 128x128 tile, BK=64, 4 waves 2x2, per-wave 4x4 16x16 fragments.
// LDS row = 128B; 16B chunks XOR-swizzled by (row&7); swizzle pre-applied on
// the GLOBAL source (linear global_load_lds destination).
template<int DUAL_A>
static __device__ __forceinline__ void gemm_core2(
    const unsigned short* __restrict__ ah, const unsigned short* __restrict__ al,
    const unsigned short* __restrict__ bh, const unsigned short* __restrict__ bl,
    unsigned short* S0, unsigned short* S1, unsigned short* S2,
    int m0, int f0, f32x4 acc[4][4]) {
  const int tid = threadIdx.x;
  const int w = tid >> 6, l = tid & 63;
  const int lg = l >> 4, lc = l & 15;
  const int wr = w >> 1, wc = w & 1;
  const int r8 = l >> 3;               // staging row within 8
  const int ch = (l & 7) ^ r8;         // pre-swizzled source chunk
  const int kc = ch * 8;               // element offset of chunk
  for (int k0 = 0; k0 < 1024; k0 += 64) {
#pragma unroll
    for (int r = 0; r < 4; ++r) {
      const int row = r*32 + w*8 + r8;
      const size_t ao = (size_t)(m0 + row)*1024 + k0 + kc;
      const size_t bo = (size_t)(f0 + row)*1024 + k0 + kc;
      const int d = r*2048 + w*512;    // shorts (lane*16B added by HW)
      gload16(S0 + d, ah + ao);
      gload16(S2 + d, bh + bo);
      if (DUAL_A) gload16(S1 + d, al + ao);
      else        gload16(S1 + d, bl + bo);
    }
    __syncthreads();
#pragma unroll
    for (int c = 0; c < 2; ++c) {
      v8h a0[4], a1[4], b0[4], b1[4];
#pragma unroll
      for (int mi = 0; mi < 4; ++mi) {
        const int row = wr*64 + mi*16 + lc;
        const int bo = row*128 + ((c*64 + lg*16) ^ ((row & 7) << 4));
        a0[mi] = *(const v8h*)((const char*)S0 + bo);
        if (DUAL_A) a1[mi] = *(const v8h*)((const char*)S1 + bo);
      }
#pragma unroll
      for (int nj = 0; nj < 4; ++nj) {
        const int row = wc*64 + nj*16 + lc;
        const int bo = row*128 + ((c*64 + lg*16) ^ ((row & 7) << 4));
        b0[nj] = *(const v8h*)((const char*)S2 + bo);
        if (!DUAL_A) b1[nj] = *(const v8h*)((const char*)S1 + bo);
      }
#pragma unroll
      for (int mi = 0; mi < 4; ++mi)
#pragma unroll
        for (int nj = 0; nj < 4; ++nj) {
          acc[mi][nj] = __builtin_amdgcn_mfma_f32_16x16x32_f16(a0[mi], b0[nj], acc[mi][nj], 0, 0, 0);
          if (DUAL_A)
            acc[mi][nj] = __builtin_amdgcn_mfma_f32_16x16x32_f16(a1[mi], b0[nj], acc[mi][nj], 0, 0, 0);
          else
            acc[mi][nj] = __builtin_amdgcn_mfma_f32_16x16x32_f16(a0[mi], b1[nj], acc[mi][nj], 0, 0, 0);
        }
    }
    __syncthreads();
  }
}

// ---------------- single-pass fp16 MFMA GEMM core: C = Ah·Bh^T ---------------
static __device__ __forceinline__ void gemm_core1(
    const unsigned short* __restrict__ ah, const unsigned short* __restrict__ bh,
    unsigned short* S0, unsigned short* S2,
    int m0, int f0, f32x4 acc[4][4]) {
  const int tid = threadIdx.x;
  const int w = tid >> 6, l = tid & 63;
  const int lg = l >> 4, lc = l & 15;
  const int wr = w >> 1, wc = w & 1;
  const int r8 = l >> 3;
  const int ch = (l & 7) ^ r8;
  const int kc = ch * 8;
  for (int k0 = 0; k0 < 1024; k0 += 64) {
#pragma unroll
    for (int r = 0; r < 4; ++r) {
      const int row = r*32 + w*8 + r8;
      const size_t ao = (size_t)(m0 + row)*1024 + k0 + kc;
      const size_t bo = (size_t)(f0 + row)*1024 + k0 + kc;
      const int d = r*2048 + w*512;
      gload16(S0 + d, ah + ao);
      gload16(S2 + d, bh + bo);
    }
    __syncthreads();
#pragma unroll
    for (int c = 0; c < 2; ++c) {
      v8h a0[4], b0[4];
#pragma unroll
      for (int mi = 0; mi < 4; ++mi) {
        const int row = wr*64 + mi*16 + lc;
        const int bo = row*128 + ((c*64 + lg*16) ^ ((row & 7) << 4));
        a0[mi] = *(const v8h*)((const char*)S0 + bo);
      }
#pragma unroll
      for (int nj = 0; nj < 4; ++nj) {
        const int row = wc*64 + nj*16 + lc;
        const int bo = row*128 + ((c*64 + lg*16) ^ ((row & 7) << 4));
        b0[nj] = *(const v8h*)((const char*)S2 + bo);
      }
#pragma unroll
      for (int mi = 0; mi < 4; ++mi)
#pragma unroll
        for (int nj = 0; nj < 4; ++nj)
          acc[mi][nj] = __builtin_amdgcn_mfma_f32_16x16x32_f16(a0[mi], b0[nj], acc[mi][nj], 0, 0, 0);
    }
    __syncthreads();
  }
}

// ---------------- QK GEMM (dual-x 2-pass) + fused RoPE + fp16 hi/lo ----------
__global__ __launch_bounds__(256) void qk_gemm_mfma(
    const unsigned short* __restrict__ xh, const unsigned short* __restrict__ xl,
    const unsigned short* __restrict__ wh,
    const float* __restrict__ cs, const float* __restrict__ sn,
    unsigned short* __restrict__ qh, unsigned short* __restrict__ ql,
    unsigned short* __restrict__ kh, unsigned short* __restrict__ kl) {
  __shared__ unsigned short S[24576];   // 48 KB
  const int tid = threadIdx.x;
  const int w = tid >> 6, l = tid & 63;
  const int lg = l >> 4, lc = l & 15;
  const int wr = w >> 1, wc = w & 1;
  const int nwg = gridDim.x * gridDim.y;   // 1024
  int bid = blockIdx.y * gridDim.x + blockIdx.x;
  bid = (bid & 7) * (nwg >> 3) + (bid >> 3);
  const int m0 = (bid / gridDim.x) * 128;
  const int f0 = (bid % gridDim.x) * 128;  // 0..1920 over q|k (2048 cols)
  f32x4 acc[4][4] = {};
  gemm_core2<1>(xh, xl, wh, wh, S, S + 8192, S + 16384, m0, f0, acc);
  const int qsel = f0 >> 10;               // 0=q, 1=k (block-uniform)
  const int head = ((f0 & 1023) >> 6) + wc;
  float* tbl = (float*)S;
  tbl[tid] = cs[tid];
  tbl[256 + tid] = sn[tid];
  __syncthreads();
  // q pre-scaled by (1/8)*log2(e) so attention works in exp2 domain
  const float scale = (qsel == 0) ? 0.18033688011112042f : 1.0f;
  unsigned short* oh = qsel ? kh : qh;
  unsigned short* ol = qsel ? kl : ql;
#pragma unroll
  for (int mi = 0; mi < 4; ++mi)
#pragma unroll
    for (int nj = 0; nj < 4; ++nj) {
      const int d = nj*16 + lc;
#pragma unroll
      for (int r = 0; r < 4; ++r) {
        const int m = m0 + wr*64 + mi*16 + lg*4 + r;
        const int b = m >> 10, n = m & 1023;
        float val = acc[mi][nj][r] * scale;
        float part = __shfl_xor(val, 1);
        if (nj < 2) {   // d < 32 -> rotated
          const int p = d >> 1;
          const int pos = (p < 8) ? (n >> 5) : (n & 31);
          const float c = tbl[pos*8 + (p & 7)];
          const float s = tbl[256 + pos*8 + (p & 7)];
          val = (d & 1) ? (val*c + part*s) : (val*c - part*s);
        }
        const unsigned short hb = f2h(val);
        const size_t off = ((size_t)(b*HEADS_ + head)*N_ + n)*HD_ + d;
        oh[off] = hb;
        ol[off] = f2h(val - h2fl(hb));
      }
    }
}

// ---------------- V GEMM (single-pass) + fused transpose + fp16 store --------
// Writes V^T directly: vth[(b*16+h)*64 + d][n], fp16 hi only.
__global__ __launch_bounds__(256) void v_gemm_mfma(
    const unsigned short* __restrict__ xh, const unsigned short* __restrict__ wh,
    unsigned short* __restrict__ vth) {
  __shared__ unsigned short S[24576];
  const int tid = threadIdx.x;
  const int w = tid >> 6, l = tid & 63;
  const int lg = l >> 4, lc = l & 15;
  const int wr = w >> 1, wc = w & 1;
  const int nwg = gridDim.x * gridDim.y;   // 512
  int bid = blockIdx.y * gridDim.x + blockIdx.x;
  bid = (bid & 7) * (nwg >> 3) + (bid >> 3);
  const int m0 = (bid / gridDim.x) * 128;
  const int f0 = (bid % gridDim.x) * 128;  // 0..896 (v block rows +2048)
  f32x4 acc[4][4] = {};
  gemm_core1(xh, wh + (size_t)2048*1024, S, S + 8192, m0, f0, acc);
  // per-wave 64x64 transpose through padded LDS (row = 72 fp16 = 144B)
  unsigned short* VT = S + w * 4608;       // 64*72 ush per wave
#pragma unroll
  for (int mi = 0; mi < 4; ++mi)
#pragma unroll
    for (int nj = 0; nj < 4; ++nj)
#pragma unroll
      for (int r = 0; r < 4; r += 2) {
        const int ml = mi*16 + lg*4 + r;
        const int dl = nj*16 + lc;
        *(unsigned*)((char*)VT + dl*144 + ml*2) = pkh2(acc[mi][nj][r], acc[mi][nj][r+1]);
      }
  __syncthreads();
  const int b = m0 >> 10;
  const int n0 = (m0 & 1023) + wr*64;
  const int head = (f0 >> 6) + wc;
#pragma unroll
  for (int j = 0; j < 8; ++j) {
    const int dl = (l >> 3) + j*8;
    u32x4 val = *(const u32x4*)((const char*)VT + dl*144 + (l & 7)*16);
    *(u32x4*)(vth + ((size_t)((b*HEADS_ + head)*HD_ + dl))*N_ + n0 + (l & 7)*8) = val;
  }
}

// ---------------- Proj GEMM (MFMA): out = att·(Wh+Wl)^T + bias ---------------
__global__ __launch_bounds__(256) void proj_gemm_mfma(
    const unsigned short* __restrict__ ah,
    const unsigned short* __restrict__ wh, const unsigned short* __restrict__ wl,
    const float* __restrict__ bias, float* __restrict__ out) {
  __shared__ unsigned short S[24576];
  const int tid = threadIdx.x;
  const int w = tid >> 6, l = tid & 63;
  const int lg = l >> 4, lc = l & 15;
  const int wr = w >> 1, wc = w & 1;
  const int nwg = gridDim.x * gridDim.y;   // 512
  int bid = blockIdx.y * gridDim.x + blockIdx.x;
  bid = (bid & 7) * (nwg >> 3) + (bid >> 3);
  const int m0 = (bid / gridDim.x) * 128;
  const int o0 = (bid % gridDim.x) * 128;
  f32x4 acc[4][4] = {};
  gemm_core2<0>(ah, ah, wh, wl, S, S + 8192, S + 16384, m0, o0, acc);
#pragma unroll
  for (int nj = 0; nj < 4; ++nj) {
    const int o = o0 + wc*64 + nj*16 + lc;
    const float bv = bias[o];
#pragma unroll
    for (int mi = 0; mi < 4; ++mi)
#pragma unroll
      for (int r = 0; r < 4; ++r) {
        const int m = m0 + wr*64 + mi*16 + lg*4 + r;
        out[(size_t)m*DIM_ + o] = acc[mi][nj][r] + bv;
      }
  }
}

// ---------------- Flash attention: swapped QK^T, fp16, QBLK=128 --------------
// PV single-pass (V fp16 hi only).
__global__ __launch_bounds__(256, 3) void attn_mfma_k(
    const unsigned short* __restrict__ qh, const unsigned short* __restrict__ ql,
    const unsigned short* __restrict__ kh, const unsigned short* __restrict__ kl,
    const unsigned short* __restrict__ vth,
    unsigned short* __restrict__ aoh) {
  __shared__ unsigned short KhS[4096], KlS[4096], VhS[4096];
  __shared__ unsigned int Pws[4][512];
  const int tid = threadIdx.x;
  const int w = tid >> 6, l = tid & 63;
  const int lg = l >> 4, lc = l & 15;
  const int bh = blockIdx.x, qt = blockIdx.y;
  const size_t gb = (size_t)bh * (N_*HD_);

  v8h qfh[2][2], qfl[2][2];
#pragma unroll
  for (int rt = 0; rt < 2; ++rt)
#pragma unroll
    for (int c = 0; c < 2; ++c) {
      const size_t off = gb + (size_t)(qt*128 + w*32 + rt*16 + lc)*HD_ + c*32 + lg*8;
      qfh[rt][c] = *(const v8h*)(qh + off);
      qfl[rt][c] = *(const v8h*)(ql + off);
    }
  f32x4 O[2][4];
#pragma unroll
  for (int rt = 0; rt < 2; ++rt)
#pragma unroll
    for (int dt = 0; dt < 4; ++dt) O[rt][dt] = (f32x4){0.f, 0.f, 0.f, 0.f};
  float mrow[2] = {-INFINITY, -INFINITY};
  float lrow[2] = {0.f, 0.f};

  const int sr8 = l >> 3;
  const int sch = (l & 7) ^ sr8;
  char* PB = (char*)&Pws[w][0];
  const int psw = (lc & 7) << 4;

  for (int t = 0; t < 16; ++t) {
#pragma unroll
    for (int i = 0; i < 2; ++i) {
      const int row = w*16 + i*8 + sr8;
      const int lbase = (w*16 + i*8)*64;
      const size_t kge = gb + (size_t)(t*64 + row)*HD_ + sch*8;
      const size_t vge = gb + (size_t)row*N_ + t*64 + sch*8;
      gload16(KhS + lbase, kh + kge);
      gload16(KlS + lbase, kl + kge);
      gload16(VhS + lbase, vth + vge);
    }
    __syncthreads();
    f32x4 s[2][4];
#pragma unroll
    for (int rt = 0; rt < 2; ++rt)
#pragma unroll
      for (int kt = 0; kt < 4; ++kt) s[rt][kt] = (f32x4){0.f, 0.f, 0.f, 0.f};
#pragma unroll
    for (int kt = 0; kt < 4; ++kt) {
      const int row = kt*16 + lc;
      const int sw = (row & 7) << 4;
#pragma unroll
      for (int c = 0; c < 2; ++c) {
        const int boff = row*128 + ((c*64 + lg*16) ^ sw);
        v8h kfh = *(const v8h*)((const char*)KhS + boff);
        v8h kfl = *(const v8h*)((const char*)KlS + boff);
#pragma unroll
        for (int rt = 0; rt < 2; ++rt) {
          s[rt][kt] = __builtin_amdgcn_mfma_f32_16x16x32_f16(kfh, qfh[rt][c], s[rt][kt], 0, 0, 0);
          s[rt][kt] = __builtin_amdgcn_mfma_f32_16x16x32_f16(kfh, qfl[rt][c], s[rt][kt], 0, 0, 0);
          s[rt][kt] = __builtin_amdgcn_mfma_f32_16x16x32_f16(kfl, qfh[rt][c], s[rt][kt], 0, 0, 0);
        }
      }
    }
    float tm[2];
#pragma unroll
    for (int rt = 0; rt < 2; ++rt) {
      float m0 = fmaxf(fmaxf(s[rt][0][0], s[rt][0][1]), fmaxf(s[rt][0][2], s[rt][0][3]));
#pragma unroll
      for (int kt = 1; kt < 4; ++kt) {
        m0 = fmaxf(m0, fmaxf(fmaxf(s[rt][kt][0], s[rt][kt][1]),
                             fmaxf(s[rt][kt][2], s[rt][kt][3])));
      }
      m0 = fmaxf(m0, __shfl_xor(m0, 16));
      m0 = fmaxf(m0, __shfl_xor(m0, 32));
      tm[rt] = m0;
    }
    const bool ok = (tm[0] <= mrow[0] + 8.f) && (tm[1] <= mrow[1] + 8.f);
    if (!__all(ok)) {
      float corr[2];
#pragma unroll
      for (int rt = 0; rt < 2; ++rt) {
        const float mn = fmaxf(mrow[rt], tm[rt]);
        corr[rt] = fexp2(mrow[rt] - mn);
        mrow[rt] = mn;
        lrow[rt] *= corr[rt];
      }
#pragma unroll
      for (int rt = 0; rt < 2; ++rt)
#pragma unroll
        for (int r = 0; r < 4; ++r) {
          const float cr = __shfl(corr[rt], lg*4 + r);
#pragma unroll
          for (int dt = 0; dt < 4; ++dt) O[rt][dt][r] *= cr;
        }
    }
    u32x4 pa[2][2];
#pragma unroll
    for (int rt = 0; rt < 2; ++rt) {
      float ps = 0.f;
      float p[4][4];
#pragma unroll
      for (int kt = 0; kt < 4; ++kt)
#pragma unroll
        for (int r = 0; r < 4; ++r) {
          const float pv = fexp2(s[rt][kt][r] - mrow[rt]);
          p[kt][r] = pv;
          ps += pv;
        }
      ps += __shfl_xor(ps, 16);
      ps += __shfl_xor(ps, 32);
      lrow[rt] += ps;
#pragma unroll
      for (int kt = 0; kt < 4; ++kt) {
        uint2 pw;
        pw.x = pkh2(p[kt][0], p[kt][1]);
        pw.y = pkh2(p[kt][2], p[kt][3]);
        *(uint2*)(PB + lc*128 + ((kt*32 + lg*8) ^ psw)) = pw;
      }
#pragma unroll
      for (int c = 0; c < 2; ++c)
        pa[rt][c] = *(const u32x4*)(PB + lc*128 + ((c*64 + lg*16) ^ psw));
    }
#pragma unroll
    for (int dt = 0; dt < 4; ++dt) {
      const int row = dt*16 + lc;
      const int sw = (row & 7) << 4;
#pragma unroll
      for (int c = 0; c < 2; ++c) {
        const int boff = row*128 + ((c*64 + lg*16) ^ sw);
        v8h vfh = *(const v8h*)((const char*)VhS + boff);
#pragma unroll
        for (int rt = 0; rt < 2; ++rt) {
          const v8h pv = __builtin_bit_cast(v8h, pa[rt][c]);
          O[rt][dt] = __builtin_amdgcn_mfma_f32_16x16x32_f16(pv, vfh, O[rt][dt], 0, 0, 0);
        }
      }
    }
    __syncthreads();
  }
  // ---- epilogue: attout fp16 hi only (proj A operand), (B, N, DIM)
  const int b = bh >> 4, h = bh & 15;
#pragma unroll
  for (int rt = 0; rt < 2; ++rt) {
    const float myinv = 1.0f / lrow[rt];
#pragma unroll
    for (int r = 0; r < 4; ++r) {
      const float iv = __shfl(myinv, lg*4 + r);
      const int n = qt*128 + w*32 + rt*16 + lg*4 + r;
      const size_t base = ((size_t)(b*N_ + n))*DIM_ + h*HD_ + lc;
#pragma unroll
      for (int dt = 0; dt < 4; ++dt)
        aoh[base + dt*16] = f2h(O[rt][dt][r] * iv);
    }
  }
}

extern "C" void kernel_launch(void* const* d_in, const int* in_sizes, int n_in,
                              void* d_out, int out_size, void* d_ws, size_t ws_size,
                              hipStream_t stream) {
  const float* x     = (const float*)d_in[0];
  const float* Wqkv  = (const float*)d_in[1];
  const float* Wproj = (const float*)d_in[2];
  const float* bproj = (const float*)d_in[3];
  float* out = (float*)d_out;

  unsigned short* xh  = (unsigned short*)d_ws;             // 8388608
  unsigned short* xl  = xh  + 8388608;                     // 8388608
  unsigned short* wqh = xl  + 8388608;                     // 3145728 (hi only)
  unsigned short* wph = wqh + 3145728;                     // 1048576
  unsigned short* wpl = wph + 1048576;                     // 1048576
  unsigned short* qh  = wpl + 1048576;                     // 8388608 x4
  unsigned short* ql  = qh  + 8388608;
  unsigned short* kh  = ql  + 8388608;
  unsigned short* kl  = kh  + 8388608;
  unsigned short* vth = kl  + 8388608;                     // 8388608 (fp16 V^T)
  float* cs = (float*)(vth + 8388608);                     // 256
  float* sn = cs + 256;                                    // 256
  unsigned short* aoh = xh;   // alias: x-splits dead after v_gemm

  hipLaunchKernelGGL(rope_table_k, dim3(1), dim3(256), 0, stream, cs, sn);
  hipLaunchKernelGGL(split2h_k, dim3(8192), dim3(256), 0, stream, x,     xh, xl, 2097152);
  hipLaunchKernelGGL(split1h_k, dim3(3072), dim3(256), 0, stream, Wqkv,  wqh, 786432);
  hipLaunchKernelGGL(split2h_k, dim3(1024), dim3(256), 0, stream, Wproj, wph, wpl, 262144);
  hipLaunchKernelGGL(qk_gemm_mfma, dim3(16, 64), dim3(256), 0, stream,
                     xh, xl, wqh, cs, sn, qh, ql, kh, kl);
  hipLaunchKernelGGL(v_gemm_mfma, dim3(8, 64), dim3(256), 0, stream, xh, wqh, vth);
  hipLaunchKernelGGL(attn_mfma_k, dim3(128, 8), dim3(256), 0, stream,
                     qh, ql, kh, kl, vth, aoh);
  hipLaunchKernelGGL(proj_gemm_mfma, dim3(8, 64), dim3(256), 0, stream,
                     aoh, wph, wpl, bproj, out);
}

// Round 8
// 231.820 us; speedup vs baseline: 9.1687x; 1.0380x over previous
//
#include <hip/hip_runtime.h>
#include <math.h>

#define DIM_ 1024
#define HEADS_ 16
#define HD_ 64
#define B_ 8
#define N_ 1024
#define M_TOT 8192

typedef __attribute__((ext_vector_type(4))) float f32x4;  // MFMA C/D
typedef _Float16 v8h __attribute__((ext_vector_type(8))); // 8 fp16
typedef __attribute__((ext_vector_type(4))) unsigned int u32x4;

static __device__ __forceinline__ unsigned short f2h(float x) {
  _Float16 h = (_Float16)x;
  return __builtin_bit_cast(unsigned short, h);
}
static __device__ __forceinline__ float h2fl(unsigned short u) {
  return (float)__builtin_bit_cast(_Float16, u);
}
static __device__ __forceinline__ float fexp2(float x) {
  return __builtin_amdgcn_exp2f(x);
}
static __device__ __forceinline__ unsigned pkh2(float a, float b) {
  auto t = __builtin_amdgcn_cvt_pkrtz(a, b);   // 2 x fp16 packed
  return __builtin_bit_cast(unsigned, t);
}

static __device__ __forceinline__ void gload16(unsigned short* lds_base,
                                               const unsigned short* g) {
  __builtin_amdgcn_global_load_lds(
      (const __attribute__((address_space(1))) unsigned int*)g,
      (__attribute__((address_space(3))) unsigned int*)lds_base, 16, 0, 0);
}

// ---------------- fp32 -> fp16 hi/lo split -----------------------------------
__global__ __launch_bounds__(256) void split2h_k(const float* __restrict__ src,
                                                 unsigned short* __restrict__ hi,
                                                 unsigned short* __restrict__ lo,
                                                 int n4) {
  int i = blockIdx.x * 256 + threadIdx.x;
  if (i >= n4) return;
  float4 x = ((const float4*)src)[i];
  ushort4 h, l;
  h.x = f2h(x.x); l.x = f2h(x.x - h2fl(h.x));
  h.y = f2h(x.y); l.y = f2h(x.y - h2fl(h.y));
  h.z = f2h(x.z); l.z = f2h(x.z - h2fl(h.z));
  h.w = f2h(x.w); l.w = f2h(x.w - h2fl(h.w));
  ((ushort4*)hi)[i] = h;
  ((ushort4*)lo)[i] = l;
}

// ---------------- fp32 -> fp16 hi only ---------------------------------------
__global__ __launch_bounds__(256) void split1h_k(const float* __restrict__ src,
                                                 unsigned short* __restrict__ hi,
                                                 int n4) {
  int i = blockIdx.x * 256 + threadIdx.x;
  if (i >= n4) return;
  float4 x = ((const float4*)src)[i];
  ushort4 h;
  h.x = f2h(x.x); h.y = f2h(x.y); h.z = f2h(x.z); h.w = f2h(x.w);
  ((ushort4*)hi)[i] = h;
}

// ---------------- RoPE table (fp64; angles reach ~1608 rad) ------------------
__global__ void rope_table_k(float* cs, float* sn) {
  int i = threadIdx.x;
  if (i < 256) {
    int pos = i >> 3, j = i & 7;
    double u = -1.0 + (double)pos * (2.0/31.0);
    double ang = u * ((1.0 + 73.0*(double)j) * 3.14159265358979323846);
    cs[i] = (float)cos(ang);
    sn[i] = (float)sin(ang);
  }
}

// ---------------- 2-pass fp16 MFMA GEMM core ---------------------------------
// DUAL_A=1: C = (Ah+Al)·Bh^T. DUAL_A=0: C = Ah·(Bh+Bl)^T.
template<int DUAL_A>
static __device__ __forceinline__ void gemm_core2(
    const unsigned short* __restrict__ ah, const unsigned short* __restrict__ al,
    const unsigned short* __restrict__ bh, const unsigned short* __restrict__ bl,
    unsigned short* S0, unsigned short* S1, unsigned short* S2,
    int m0, int f0, f32x4 acc[4][4]) {
  const int tid = threadIdx.x;
  const int w = tid >> 6, l = tid & 63;
  const int lg = l >> 4, lc = l & 15;
  const int wr = w >> 1, wc = w & 1;
  const int r8 = l >> 3;               // staging row within 8
  const int ch = (l & 7) ^ r8;         // pre-swizzled source chunk
  const int kc = ch * 8;               // element offset of chunk
  for (int k0 = 0; k0 < 1024; k0 += 64) {
#pragma unroll
    for (int r = 0; r < 4; ++r) {
      const int row = r*32 + w*8 + r8;
      const size_t ao = (size_t)(m0 + row)*1024 + k0 + kc;
      const size_t bo = (size_t)(f0 + row)*1024 + k0 + kc;
      const int d = r*2048 + w*512;    // shorts (lane*16B added by HW)
      gload16(S0 + d, ah + ao);
      gload16(S2 + d, bh + bo);
      if (DUAL_A) gload16(S1 + d, al + ao);
      else        gload16(S1 + d, bl + bo);
    }
    __syncthreads();
#pragma unroll
    for (int c = 0; c < 2; ++c) {
      v8h a0[4], a1[4], b0[4], b1[4];
#pragma unroll
      for (int mi = 0; mi < 4; ++mi) {
        const int row = wr*64 + mi*16 + lc;
        const int bo = row*128 + ((c*64 + lg*16) ^ ((row & 7) << 4));
        a0[mi] = *(const v8h*)((const char*)S0 + bo);
        if (DUAL_A) a1[mi] = *(const v8h*)((const char*)S1 + bo);
      }
#pragma unroll
      for (int nj = 0; nj < 4; ++nj) {
        const int row = wc*64 + nj*16 + lc;
        const int bo = row*128 + ((c*64 + lg*16) ^ ((row & 7) << 4));
        b0[nj] = *(const v8h*)((const char*)S2 + bo);
        if (!DUAL_A) b1[nj] = *(const v8h*)((const char*)S1 + bo);
      }
#pragma unroll
      for (int mi = 0; mi < 4; ++mi)
#pragma unroll
        for (int nj = 0; nj < 4; ++nj) {
          acc[mi][nj] = __builtin_amdgcn_mfma_f32_16x16x32_f16(a0[mi], b0[nj], acc[mi][nj], 0, 0, 0);
          if (DUAL_A)
            acc[mi][nj] = __builtin_amdgcn_mfma_f32_16x16x32_f16(a1[mi], b0[nj], acc[mi][nj], 0, 0, 0);
          else
            acc[mi][nj] = __builtin_amdgcn_mfma_f32_16x16x32_f16(a0[mi], b1[nj], acc[mi][nj], 0, 0, 0);
        }
    }
    __syncthreads();
  }
}

// ---------------- single-pass fp16 MFMA GEMM core: C = Ah·Bh^T ---------------
static __device__ __forceinline__ void gemm_core1(
    const unsigned short* __restrict__ ah, const unsigned short* __restrict__ bh,
    unsigned short* S0, unsigned short* S2,
    int m0, int f0, f32x4 acc[4][4]) {
  const int tid = threadIdx.x;
  const int w = tid >> 6, l = tid & 63;
  const int lg = l >> 4, lc = l & 15;
  const int wr = w >> 1, wc = w & 1;
  const int r8 = l >> 3;
  const int ch = (l & 7) ^ r8;
  const int kc = ch * 8;
  for (int k0 = 0; k0 < 1024; k0 += 64) {
#pragma unroll
    for (int r = 0; r < 4; ++r) {
      const int row = r*32 + w*8 + r8;
      const size_t ao = (size_t)(m0 + row)*1024 + k0 + kc;
      const size_t bo = (size_t)(f0 + row)*1024 + k0 + kc;
      const int d = r*2048 + w*512;
      gload16(S0 + d, ah + ao);
      gload16(S2 + d, bh + bo);
    }
    __syncthreads();
#pragma unroll
    for (int c = 0; c < 2; ++c) {
      v8h a0[4], b0[4];
#pragma unroll
      for (int mi = 0; mi < 4; ++mi) {
        const int row = wr*64 + mi*16 + lc;
        const int bo = row*128 + ((c*64 + lg*16) ^ ((row & 7) << 4));
        a0[mi] = *(const v8h*)((const char*)S0 + bo);
      }
#pragma unroll
      for (int nj = 0; nj < 4; ++nj) {
        const int row = wc*64 + nj*16 + lc;
        const int bo = row*128 + ((c*64 + lg*16) ^ ((row & 7) << 4));
        b0[nj] = *(const v8h*)((const char*)S2 + bo);
      }
#pragma unroll
      for (int mi = 0; mi < 4; ++mi)
#pragma unroll
        for (int nj = 0; nj < 4; ++nj)
          acc[mi][nj] = __builtin_amdgcn_mfma_f32_16x16x32_f16(a0[mi], b0[nj], acc[mi][nj], 0, 0, 0);
    }
    __syncthreads();
  }
}

// ---------------- QK GEMM (dual-x 2-pass) + fused RoPE -----------------------
// q stored fp16 hi/lo; k stored fp16 hi only (2-pass QK^T in attention).
__global__ __launch_bounds__(256) void qk_gemm_mfma(
    const unsigned short* __restrict__ xh, const unsigned short* __restrict__ xl,
    const unsigned short* __restrict__ wh,
    const float* __restrict__ cs, const float* __restrict__ sn,
    unsigned short* __restrict__ qh, unsigned short* __restrict__ ql,
    unsigned short* __restrict__ kh) {
  __shared__ unsigned short S[24576];   // 48 KB
  const int tid = threadIdx.x;
  const int w = tid >> 6, l = tid & 63;
  const int lg = l >> 4, lc = l & 15;
  const int wr = w >> 1, wc = w & 1;
  const int nwg = gridDim.x * gridDim.y;   // 1024
  int bid = blockIdx.y * gridDim.x + blockIdx.x;
  bid = (bid & 7) * (nwg >> 3) + (bid >> 3);
  const int m0 = (bid / gridDim.x) * 128;
  const int f0 = (bid % gridDim.x) * 128;  // 0..1920 over q|k (2048 cols)
  f32x4 acc[4][4] = {};
  gemm_core2<1>(xh, xl, wh, wh, S, S + 8192, S + 16384, m0, f0, acc);
  const int qsel = f0 >> 10;               // 0=q, 1=k (block-uniform)
  const int head = ((f0 & 1023) >> 6) + wc;
  float* tbl = (float*)S;
  tbl[tid] = cs[tid];
  tbl[256 + tid] = sn[tid];
  __syncthreads();
  // q pre-scaled by (1/8)*log2(e) so attention works in exp2 domain
  const float scale = (qsel == 0) ? 0.18033688011112042f : 1.0f;
  unsigned short* oh = qsel ? kh : qh;
#pragma unroll
  for (int mi = 0; mi < 4; ++mi)
#pragma unroll
    for (int nj = 0; nj < 4; ++nj) {
      const int d = nj*16 + lc;
#pragma unroll
      for (int r = 0; r < 4; ++r) {
        const int m = m0 + wr*64 + mi*16 + lg*4 + r;
        const int b = m >> 10, n = m & 1023;
        float val = acc[mi][nj][r] * scale;
        float part = __shfl_xor(val, 1);
        if (nj < 2) {   // d < 32 -> rotated
          const int p = d >> 1;
          const int pos = (p < 8) ? (n >> 5) : (n & 31);
          const float c = tbl[pos*8 + (p & 7)];
          const float s = tbl[256 + pos*8 + (p & 7)];
          val = (d & 1) ? (val*c + part*s) : (val*c - part*s);
        }
        const unsigned short hb = f2h(val);
        const size_t off = ((size_t)(b*HEADS_ + head)*N_ + n)*HD_ + d;
        oh[off] = hb;
        if (qsel == 0) ql[off] = f2h(val - h2fl(hb));
      }
    }
}

// ---------------- V GEMM (single-pass) + fused transpose + fp16 store --------
__global__ __launch_bounds__(256) void v_gemm_mfma(
    const unsigned short* __restrict__ xh, const unsigned short* __restrict__ wh,
    unsigned short* __restrict__ vth) {
  __shared__ unsigned short S[24576];
  const int tid = threadIdx.x;
  const int w = tid >> 6, l = tid & 63;
  const int lg = l >> 4, lc = l & 15;
  const int wr = w >> 1, wc = w & 1;
  const int nwg = gridDim.x * gridDim.y;   // 512
  int bid = blockIdx.y * gridDim.x + blockIdx.x;
  bid = (bid & 7) * (nwg >> 3) + (bid >> 3);
  const int m0 = (bid / gridDim.x) * 128;
  const int f0 = (bid % gridDim.x) * 128;
  f32x4 acc[4][4] = {};
  gemm_core1(xh, wh + (size_t)2048*1024, S, S + 8192, m0, f0, acc);
  // per-wave 64x64 transpose through padded LDS (row = 72 fp16 = 144B)
  unsigned short* VT = S + w * 4608;
#pragma unroll
  for (int mi = 0; mi < 4; ++mi)
#pragma unroll
    for (int nj = 0; nj < 4; ++nj)
#pragma unroll
      for (int r = 0; r < 4; r += 2) {
        const int ml = mi*16 + lg*4 + r;
        const int dl = nj*16 + lc;
        *(unsigned*)((char*)VT + dl*144 + ml*2) = pkh2(acc[mi][nj][r], acc[mi][nj][r+1]);
      }
  __syncthreads();
  const int b = m0 >> 10;
  const int n0 = (m0 & 1023) + wr*64;
  const int head = (f0 >> 6) + wc;
#pragma unroll
  for (int j = 0; j < 8; ++j) {
    const int dl = (l >> 3) + j*8;
    u32x4 val = *(const u32x4*)((const char*)VT + dl*144 + (l & 7)*16);
    *(u32x4*)(vth + ((size_t)((b*HEADS_ + head)*HD_ + dl))*N_ + n0 + (l & 7)*8) = val;
  }
}

// ---------------- Proj GEMM (MFMA): out = att·(Wh+Wl)^T + bias ---------------
__global__ __launch_bounds__(256) void proj_gemm_mfma(
    const unsigned short* __restrict__ ah,
    const unsigned short* __restrict__ wh, const unsigned short* __restrict__ wl,
    const float* __restrict__ bias, float* __restrict__ out) {
  __shared__ unsigned short S[24576];
  const int tid = threadIdx.x;
  const int w = tid >> 6, l = tid & 63;
  const int lg = l >> 4, lc = l & 15;
  const int wr = w >> 1, wc = w & 1;
  const int nwg = gridDim.x * gridDim.y;   // 512
  int bid = blockIdx.y * gridDim.x + blockIdx.x;
  bid = (bid & 7) * (nwg >> 3) + (bid >> 3);
  const int m0 = (bid / gridDim.x) * 128;
  const int o0 = (bid % gridDim.x) * 128;
  f32x4 acc[4][4] = {};
  gemm_core2<0>(ah, ah, wh, wl, S, S + 8192, S + 16384, m0, o0, acc);
#pragma unroll
  for (int nj = 0; nj < 4; ++nj) {
    const int o = o0 + wc*64 + nj*16 + lc;
    const float bv = bias[o];
#pragma unroll
    for (int mi = 0; mi < 4; ++mi)
#pragma unroll
      for (int r = 0; r < 4; ++r) {
        const int m = m0 + wr*64 + mi*16 + lg*4 + r;
        out[(size_t)m*DIM_ + o] = acc[mi][nj][r] + bv;
      }
  }
}

// ---------------- Flash attention: KVBLK=128, 2-pass QK, 1-pass PV -----------
// Block = (bh, qt): 128 q-rows, 4 waves x 32 rows (2 sequential row-tiles).
// S^T = mfma(K, Q): lane holds q-row = lc, keys kt*16 + lg*4 + r.
__global__ __launch_bounds__(256, 3) void attn_mfma_k(
    const unsigned short* __restrict__ qh, const unsigned short* __restrict__ ql,
    const unsigned short* __restrict__ kh,
    const unsigned short* __restrict__ vth,
    unsigned short* __restrict__ aoh) {
  __shared__ unsigned short KhS[8192];   // 128 keys x 64 d (128B rows, swizzled)
  __shared__ unsigned short VhS[8192];   // 64 d x 128 keys (256B rows, swizzled)
  __shared__ unsigned int Pws[4][1024];  // per-wave P: 16 q x 128 keys fp16
  const int tid = threadIdx.x;
  const int w = tid >> 6, l = tid & 63;
  const int lg = l >> 4, lc = l & 15;
  const int bh = blockIdx.x, qt = blockIdx.y;   // bh%8 fixed per XCD
  const size_t gb = (size_t)bh * (N_*HD_);

  v8h qfh[2][2], qfl[2][2];
#pragma unroll
  for (int rt = 0; rt < 2; ++rt)
#pragma unroll
    for (int c = 0; c < 2; ++c) {
      const size_t off = gb + (size_t)(qt*128 + w*32 + rt*16 + lc)*HD_ + c*32 + lg*8;
      qfh[rt][c] = *(const v8h*)(qh + off);
      qfl[rt][c] = *(const v8h*)(ql + off);
    }
  f32x4 O[2][4];
#pragma unroll
  for (int rt = 0; rt < 2; ++rt)
#pragma unroll
    for (int dt = 0; dt < 4; ++dt) O[rt][dt] = (f32x4){0.f, 0.f, 0.f, 0.f};
  float mrow[2] = {-INFINITY, -INFINITY};
  float lrow[2] = {0.f, 0.f};

  // staging lane constants (pre-swizzled global source, linear LDS dest)
  const int kr  = l >> 3;                        // K row within 8
  const int kch = (l & 7) ^ kr;                  // K source chunk (8 x 16B/row)
  const int vr  = l >> 4;                        // V row within 4
  const int vch = (l & 15) ^ ((w*4 + vr) & 7);   // V source chunk (16 x 16B/row)
  char* PB = (char*)&Pws[w][0];
  const int psw = (lc & 7) << 4;

  for (int t = 0; t < 8; ++t) {
#pragma unroll
    for (int i = 0; i < 4; ++i) {
      const size_t kge = gb + (size_t)(t*128 + i*32 + w*8 + kr)*HD_ + kch*8;
      const size_t vge = gb + (size_t)(i*16 + w*4 + vr)*N_ + t*128 + vch*8;
      gload16(KhS + i*2048 + w*512, kh + kge);
      gload16(VhS + i*2048 + w*512, vth + vge);
    }
    __syncthreads();
#pragma unroll
    for (int rt = 0; rt < 2; ++rt) {
      // ---- QK^T swapped: 2-pass (kh x qh, kh x ql)
      f32x4 s[8];
#pragma unroll
      for (int kt = 0; kt < 8; ++kt) {
        s[kt] = (f32x4){0.f, 0.f, 0.f, 0.f};
        const int row = kt*16 + lc;
#pragma unroll
        for (int c = 0; c < 2; ++c) {
          const int boff = row*128 + ((c*64 + lg*16) ^ psw);
          v8h kf = *(const v8h*)((const char*)KhS + boff);
          s[kt] = __builtin_amdgcn_mfma_f32_16x16x32_f16(kf, qfh[rt][c], s[kt], 0, 0, 0);
          s[kt] = __builtin_amdgcn_mfma_f32_16x16x32_f16(kf, qfl[rt][c], s[kt], 0, 0, 0);
        }
      }
      // ---- tile max for q=lc across kt/r (in-lane) then lg groups (shfl)
      float tm = fmaxf(fmaxf(s[0][0], s[0][1]), fmaxf(s[0][2], s[0][3]));
#pragma unroll
      for (int kt = 1; kt < 8; ++kt)
        tm = fmaxf(tm, fmaxf(fmaxf(s[kt][0], s[kt][1]), fmaxf(s[kt][2], s[kt][3])));
      tm = fmaxf(tm, __shfl_xor(tm, 16));
      tm = fmaxf(tm, __shfl_xor(tm, 32));
      // ---- defer-max rescale (exp2 domain, THR=8)
      if (!__all(tm <= mrow[rt] + 8.f)) {
        const float mn = fmaxf(mrow[rt], tm);
        const float corr = fexp2(mrow[rt] - mn);
        mrow[rt] = mn;
        lrow[rt] *= corr;
#pragma unroll
        for (int r = 0; r < 4; ++r) {
          const float cr = __shfl(corr, lg*4 + r);
#pragma unroll
          for (int dt = 0; dt < 4; ++dt) O[rt][dt][r] *= cr;
        }
      }
      // ---- P = exp2(s - m), row sum, pack fp16 into per-wave LDS
      float ps = 0.f;
#pragma unroll
      for (int kt = 0; kt < 8; ++kt) {
        const float p0 = fexp2(s[kt][0] - mrow[rt]);
        const float p1 = fexp2(s[kt][1] - mrow[rt]);
        const float p2 = fexp2(s[kt][2] - mrow[rt]);
        const float p3 = fexp2(s[kt][3] - mrow[rt]);
        ps += (p0 + p1) + (p2 + p3);
        uint2 pw;
        pw.x = pkh2(p0, p1);
        pw.y = pkh2(p2, p3);
        *(uint2*)(PB + lc*256 + ((kt*32 + lg*8) ^ psw)) = pw;
      }
      ps += __shfl_xor(ps, 16);
      ps += __shfl_xor(ps, 32);
      lrow[rt] += ps;
      u32x4 pa[4];
#pragma unroll
      for (int c = 0; c < 4; ++c)
        pa[c] = *(const u32x4*)(PB + lc*256 + ((c*64 + lg*16) ^ psw));
      // ---- PV: O += P·Vh (single pass)
#pragma unroll
      for (int dt = 0; dt < 4; ++dt) {
        const int row = dt*16 + lc;
#pragma unroll
        for (int c = 0; c < 4; ++c) {
          const int boff = row*256 + ((c*64 + lg*16) ^ psw);
          v8h vf = *(const v8h*)((const char*)VhS + boff);
          O[rt][dt] = __builtin_amdgcn_mfma_f32_16x16x32_f16(
              __builtin_bit_cast(v8h, pa[c]), vf, O[rt][dt], 0, 0, 0);
        }
      }
    }
    __syncthreads();
  }
  // ---- epilogue: attout fp16 hi only (proj A operand), (B, N, DIM)
  const int b = bh >> 4, h = bh & 15;
#pragma unroll
  for (int rt = 0; rt < 2; ++rt) {
    const float myinv = 1.0f / lrow[rt];
#pragma unroll
    for (int r = 0; r < 4; ++r) {
      const float iv = __shfl(myinv, lg*4 + r);
      const int n = qt*128 + w*32 + rt*16 + lg*4 + r;
      const size_t base = ((size_t)(b*N_ + n))*DIM_ + h*HD_ + lc;
#pragma unroll
      for (int dt = 0; dt < 4; ++dt)
        aoh[base + dt*16] = f2h(O[rt][dt][r] * iv);
    }
  }
}

extern "C" void kernel_launch(void* const* d_in, const int* in_sizes, int n_in,
                              void* d_out, int out_size, void* d_ws, size_t ws_size,
                              hipStream_t stream) {
  const float* x     = (const float*)d_in[0];
  const float* Wqkv  = (const float*)d_in[1];
  const float* Wproj = (const float*)d_in[2];
  const float* bproj = (const float*)d_in[3];
  float* out = (float*)d_out;

  unsigned short* xh  = (unsigned short*)d_ws;             // 8388608
  unsigned short* xl  = xh  + 8388608;                     // 8388608
  unsigned short* wqh = xl  + 8388608;                     // 3145728 (hi only)
  unsigned short* wph = wqh + 3145728;                     // 1048576
  unsigned short* wpl = wph + 1048576;                     // 1048576
  unsigned short* qh  = wpl + 1048576;                     // 8388608 x3
  unsigned short* ql  = qh  + 8388608;
  unsigned short* kh  = ql  + 8388608;
  unsigned short* vth = kh  + 8388608;                     // 8388608 (fp16 V^T)
  float* cs = (float*)(vth + 8388608);                     // 256
  float* sn = cs + 256;                                    // 256
  unsigned short* aoh = xh;   // alias: x-splits dead after v_gemm

  hipLaunchKernelGGL(rope_table_k, dim3(1), dim3(256), 0, stream, cs, sn);
  hipLaunchKernelGGL(split2h_k, dim3(8192), dim3(256), 0, stream, x,     xh, xl, 2097152);
  hipLaunchKernelGGL(split1h_k, dim3(3072), dim3(256), 0, stream, Wqkv,  wqh, 786432);
  hipLaunchKernelGGL(split2h_k, dim3(1024), dim3(256), 0, stream, Wproj, wph, wpl, 262144);
  hipLaunchKernelGGL(qk_gemm_mfma, dim3(16, 64), dim3(256), 0, stream,
                     xh, xl, wqh, cs, sn, qh, ql, kh);
  hipLaunchKernelGGL(v_gemm_mfma, dim3(8, 64), dim3(256), 0, stream, xh, wqh, vth);
  hipLaunchKernelGGL(attn_mfma_k, dim3(128, 8), dim3(256), 0, stream,
                     qh, ql, kh, vth, aoh);
  hipLaunchKernelGGL(proj_gemm_mfma, dim3(8, 64), dim3(256), 0, stream,
                     aoh, wph, wpl, bproj, out);
}